// Round 17
// baseline (332.913 us; speedup 1.0000x reference)
//
#include <hip/hip_runtime.h>
#include <cstdint>
#include <cstddef>

#define NN 50000
#define NE 800000
#define NBLK ((NN + 255) / 256)   // 196 node-chunks

typedef _Float16 f16x8 __attribute__((ext_vector_type(8)));
typedef _Float16 f16x4 __attribute__((ext_vector_type(4)));
typedef float f32x4 __attribute__((ext_vector_type(4)));

// ---------------------------------------------------------------------------
// Edge-index dtype robustness (int64 vs int32 canonicalization)
// ---------------------------------------------------------------------------
__device__ __forceinline__ int edge_at(const void* e, int is32, long long i) {
    return is32 ? ((const int*)e)[i] : (int)((const long long*)e)[i];
}

__global__ __launch_bounds__(64) void zero_flag_k(int* flag) {
    if (threadIdx.x == 0) *flag = 0;
}

__global__ __launch_bounds__(256) void detect_k(const int* __restrict__ w, int* __restrict__ flag) {
    int i = blockIdx.x * 256 + threadIdx.x;   // 0..1023
    if (i < 1024 && w[2 * i + 1] != 0) atomicOr(flag, 1);
}

// ---------------------------------------------------------------------------
// Atomic targets strided to ONE PER 128B LINE (32 ints) — r16 verified:
// removes same-line coherent-RMW serialization (scatter 50->sub-top5).
// ---------------------------------------------------------------------------
__global__ __launch_bounds__(256) void init_k(int* __restrict__ dacc,
                                              int* __restrict__ cursorS, int n) {
    int i = blockIdx.x * 256 + threadIdx.x;
    if (i < n) { dacc[(size_t)i * 32] = 1; cursorS[(size_t)i * 32] = 0; }
}

__global__ __launch_bounds__(256) void count_k(const void* __restrict__ edges,
                                               const int* __restrict__ flag,
                                               int* __restrict__ dacc, int e) {
    int i = blockIdx.x * 256 + threadIdx.x;
    if (i < e) {
        int is32 = *flag;
        atomicAdd(&dacc[(size_t)edge_at(edges, is32, i) * 32], 1);
    }
}

__global__ __launch_bounds__(256) void dcompact_k(const int* __restrict__ dacc,
                                                  int* __restrict__ deg, int n) {
    int i = blockIdx.x * 256 + threadIdx.x;
    if (i < n) deg[i] = dacc[(size_t)i * 32];
}

// ---------------------------------------------------------------------------
// Degree-sorted node permutation, contention-free 3-phase counting sort.
// ---------------------------------------------------------------------------
__global__ __launch_bounds__(256) void bh_k(const int* __restrict__ deg,
                                            int* __restrict__ bh, int n) {
    __shared__ int lh[1024];
    int t = threadIdx.x;
    for (int b = t; b < 1024; b += 256) lh[b] = 0;
    __syncthreads();
    int i = blockIdx.x * 256 + t;
    if (i < n) atomicAdd(&lh[min(deg[i], 1023)], 1);
    __syncthreads();
    for (int b = t; b < 1024; b += 256) bh[(size_t)blockIdx.x * 1024 + b] = lh[b];
}

__global__ __launch_bounds__(256) void btot_k(const int* __restrict__ bh,
                                              int* __restrict__ tot, int nb) {
    __shared__ int red[256];
    int b = blockIdx.x, t = threadIdx.x;
    int s = 0;
    for (int blk = t; blk < nb; blk += 256) s += bh[(size_t)blk * 1024 + b];
    red[t] = s;
    __syncthreads();
    for (int off = 128; off; off >>= 1) {
        if (t < off) red[t] += red[t + off];
        __syncthreads();
    }
    if (t == 0) tot[b] = red[0];
}

__global__ __launch_bounds__(1024) void hscan_k(const int* __restrict__ hist,
                                                int* __restrict__ bcur) {
    __shared__ int s[1024];
    int t = threadIdx.x;
    s[t] = hist[t];
    __syncthreads();
    for (int off = 1; off < 1024; off <<= 1) {
        int val = (t >= off) ? s[t - off] : 0;
        __syncthreads();
        s[t] += val;
        __syncthreads();
    }
    bcur[t] = (t == 0) ? 0 : s[t - 1];
}

__global__ __launch_bounds__(256) void bbase_k(int* __restrict__ bh,
                                               const int* __restrict__ bstart, int nb) {
    __shared__ int s[256];
    int b = blockIdx.x, t = threadIdx.x;
    int v = (t < nb) ? bh[(size_t)t * 1024 + b] : 0;
    s[t] = v;
    __syncthreads();
    for (int off = 1; off < 256; off <<= 1) {
        int x = (t >= off) ? s[t - off] : 0;
        __syncthreads();
        s[t] += x;
        __syncthreads();
    }
    int excl = (t == 0) ? 0 : s[t - 1];
    if (t < nb) bh[(size_t)t * 1024 + b] = bstart[b] + excl;
}

__global__ __launch_bounds__(256) void pscatter_k(const int* __restrict__ deg,
                                                  const int* __restrict__ bh,
                                                  int* __restrict__ perm,
                                                  int* __restrict__ inv_perm, int n) {
    __shared__ int lh[1024];
    int t = threadIdx.x;
    for (int b = t; b < 1024; b += 256) lh[b] = 0;
    __syncthreads();
    int i = blockIdx.x * 256 + t;
    int b = 0, r = 0;
    if (i < n) {
        b = min(deg[i], 1023);
        r = atomicAdd(&lh[b], 1);
    }
    __syncthreads();
    if (i < n) {
        int pos = bh[(size_t)blockIdx.x * 1024 + b] + r;
        perm[pos] = i;
        inv_perm[i] = pos;
    }
}

// slot-space degree + dinv
__global__ __launch_bounds__(256) void degs_k(const int* __restrict__ deg,
                                              const int* __restrict__ perm,
                                              int* __restrict__ deg_s,
                                              float* __restrict__ dinv_s, int n) {
    int i = blockIdx.x * 256 + threadIdx.x;
    if (i < n) {
        int d = deg[perm[i]];
        deg_s[i] = d;
        dinv_s[i] = rsqrtf((float)d);
    }
}

// ---------------------------------------------------------------------------
// Device-wide exclusive scan of (deg_s[i]-1) -> rp[0..n] (slot space)
// ---------------------------------------------------------------------------
__global__ __launch_bounds__(256) void ppart_k(const int* __restrict__ deg,
                                               int* __restrict__ part, int n) {
    __shared__ int red[256];
    int t = threadIdx.x;
    int i = blockIdx.x * 256 + t;
    red[t] = (i < n) ? deg[i] - 1 : 0;
    __syncthreads();
    for (int off = 128; off; off >>= 1) {
        if (t < off) red[t] += red[t + off];
        __syncthreads();
    }
    if (t == 0) part[blockIdx.x] = red[0];
}

__global__ __launch_bounds__(256) void pscan1_k(int* __restrict__ part, int nb) {
    __shared__ int s[256];
    int t = threadIdx.x;
    s[t] = (t < nb) ? part[t] : 0;
    __syncthreads();
    for (int off = 1; off < 256; off <<= 1) {
        int v = (t >= off) ? s[t - off] : 0;
        __syncthreads();
        s[t] += v;
        __syncthreads();
    }
    if (t < nb) part[t] = (t == 0) ? 0 : s[t - 1];
}

__global__ __launch_bounds__(256) void pwrite_k(const int* __restrict__ deg,
                                                const int* __restrict__ part,
                                                int* __restrict__ rp, int n) {
    __shared__ int s[256];
    int t = threadIdx.x;
    int i = blockIdx.x * 256 + t;
    int val = (i < n) ? deg[i] - 1 : 0;
    s[t] = val;
    __syncthreads();
    for (int off = 1; off < 256; off <<= 1) {
        int v = (t >= off) ? s[t - off] : 0;
        __syncthreads();
        s[t] += v;
        __syncthreads();
    }
    int incl = s[t];
    if (i < n) rp[i] = part[blockIdx.x] + incl - val;
    if (i == n - 1) rp[n] = part[blockIdx.x] + incl;
}

// CSR scatter with renumbering; strided (1-per-line) cursors; uint16 cols.
__global__ __launch_bounds__(256) void scatter_k(const void* __restrict__ edges,
                                                 const int* __restrict__ flag,
                                                 const int* __restrict__ inv_perm,
                                                 const int* __restrict__ rp,
                                                 int* __restrict__ cursorS,
                                                 unsigned short* __restrict__ col_s, int e) {
    int i = blockIdx.x * 256 + threadIdx.x;
    if (i < e) {
        int is32 = *flag;
        int r = inv_perm[edge_at(edges, is32, i)];
        int c = inv_perm[edge_at(edges, is32, (long long)NE + i)];
        int pos = rp[r] + atomicAdd(&cursorS[(size_t)r * 32], 1);
        col_s[pos] = (unsigned short)c;
    }
}

// ---------------------------------------------------------------------------
// Hadamard v2: 4 slots per wave. Load 4 perm entries, then issue all 8 row
// gathers (4x qe + 4x obj, independent) before compute/store -> 4x MLP on
// the scattered 1KB-row reads (r16: dependent perm->load chain at 2 loads/
// thread held hadamard to 2.8 TB/s logical).
// ---------------------------------------------------------------------------
__global__ __launch_bounds__(256) void hadamard_k(const float4* __restrict__ a,
                                                  const float4* __restrict__ b,
                                                  const int* __restrict__ perm,
                                                  _Float16* __restrict__ Xh, int n) {
    int wave = (blockIdx.x * 256 + threadIdx.x) >> 6;
    int lane = threadIdx.x & 63;
    int slot0 = wave * 4;
    if (slot0 >= n) return;
    int vs[4];
    #pragma unroll
    for (int u = 0; u < 4; ++u)
        vs[u] = (slot0 + u < n) ? perm[slot0 + u] : perm[slot0];
    float4 xa[4], xb[4];
    #pragma unroll
    for (int u = 0; u < 4; ++u) xa[u] = a[(size_t)vs[u] * 64 + lane];
    #pragma unroll
    for (int u = 0; u < 4; ++u) xb[u] = b[(size_t)vs[u] * 64 + lane];
    int cq = lane * 4;
    size_t poff = ((size_t)(cq >> 5) * NN) * 32 + (cq & 31);
    #pragma unroll
    for (int u = 0; u < 4; ++u) {
        int slot = slot0 + u;
        if (slot >= n) break;
        f16x4 hh;
        hh[0] = (_Float16)(xa[u].x * xb[u].x);
        hh[1] = (_Float16)(xa[u].y * xb[u].y);
        hh[2] = (_Float16)(xa[u].z * xb[u].z);
        hh[3] = (_Float16)(xa[u].w * xb[u].w);
        *(f16x4*)&Xh[poff + (size_t)slot * 32] = hh;
    }
}

// ---------------------------------------------------------------------------
// W convert: W[K=256][Nout] fp32 -> B3 [Nout][512] fp16, layout [Wh | Wl]
// ---------------------------------------------------------------------------
__global__ __launch_bounds__(256) void wconv_k(const float* __restrict__ W,
                                               _Float16* __restrict__ B3, int Nout) {
    int n = blockIdx.x;            // 0..Nout-1
    int k = threadIdx.x;           // 0..255
    float v = W[(size_t)k * Nout + n];
    _Float16 h = (_Float16)v;
    B3[(size_t)n * 512 + k]       = h;
    B3[(size_t)n * 512 + 256 + k] = (_Float16)(v - (float)h);
}

// ---------------------------------------------------------------------------
// fp16 MFMA GEMM over virtual K=512, slot-major panels, double-buffered LDS,
// XOR chunk-swizzle. Epilogue writes G = dinv_s[row] * (A@W).
// ---------------------------------------------------------------------------
__device__ __forceinline__ void gload_lds16(const void* g, void* l) {
    __builtin_amdgcn_global_load_lds(
        (const __attribute__((address_space(1))) void*)g,
        (__attribute__((address_space(3))) void*)l, 16, 0, 0);
}

template <int NBX, int SW>
__global__ __launch_bounds__(256) void gemm_f16_k(const _Float16* __restrict__ Ah,
                                                  const _Float16* __restrict__ B3,
                                                  const float* __restrict__ dinv_s,
                                                  _Float16* __restrict__ C,
                                                  int M, int Nout) {
    __shared__ alignas(16) _Float16 sA[2][128 * 32];
    __shared__ alignas(16) _Float16 sB[2][128 * 32];
    constexpr int LG = (SW == 32) ? 5 : 4;
    constexpr int NST = 16;           // K = 512 / 32
    int mblk = (M + 127) >> 7;

    int pair, xb;
    if (NBX == 2) {
        int b = blockIdx.x;
        pair = (b >> 4) * 8 + (b & 7);     // row-panel id; pinned to XCD (b&7)
        xb   = (b >> 3) & 1;
        if (pair >= mblk) return;
    } else {
        pair = blockIdx.x;
        xb = 0;
    }

    int tid = threadIdx.x;
    int row0 = pair * 128, col0 = xb * 128;
    int wid = tid >> 6, lane = tid & 63;
    int wm = wid >> 1, wn = wid & 1;
    int fr = lane & 15;
    int kbc = lane >> 4;            // k chunk index 0..3 (8 fp16 each)

    int sr = lane >> 2;             // staging row within 16-row chunk
    int ke = (((lane & 3) ^ ((sr >> 1) & 3)) * 8);   // pre-swizzled source chunk

    f32x4 acc[4][4] = {};

    auto STAGE = [&](int bsel, int s) {
        int p = s & 7;                    // A k-panel index
        #pragma unroll
        for (int c = 0; c < 2; ++c) {
            int ch = wid * 2 + c;         // 0..7
            int r = ch * 16 + sr;
            int arow = row0 + r;
            if (arow < M)
                gload_lds16(&Ah[((size_t)p * M + arow) * 32 + ke], &sA[bsel][ch * 512]);
            gload_lds16(&B3[(size_t)(col0 + r) * 512 + s * 32 + ke], &sB[bsel][ch * 512]);
        }
    };

    STAGE(0, 0);
    __syncthreads();
    int cur = 0;

    for (int s = 0; s < NST; ++s) {
        if (s + 1 < NST) STAGE(cur ^ 1, s + 1);

        f16x8 af[4];
        #pragma unroll
        for (int f = 0; f < 4; ++f) {
            int rr = wm * 64 + f * 16 + fr;
            af[f] = *(const f16x8*)&sA[cur][rr * 32 + ((kbc ^ ((rr >> 1) & 3)) * 8)];
        }
        #pragma unroll
        for (int g = 0; g < 4; ++g) {
            int cc = wn * 64 + g * 16 + fr;
            f16x8 bf_ = *(const f16x8*)&sB[cur][cc * 32 + ((kbc ^ ((cc >> 1) & 3)) * 8)];
            #pragma unroll
            for (int f = 0; f < 4; ++f)
                acc[f][g] = __builtin_amdgcn_mfma_f32_16x16x32_f16(af[f], bf_, acc[f][g], 0, 0, 0);
        }

        __syncthreads();
        cur ^= 1;
    }

    int rsub = (lane >> 4) * 4;
    float dsc[4][4];
    #pragma unroll
    for (int f = 0; f < 4; ++f)
        #pragma unroll
        for (int r = 0; r < 4; ++r) {
            int row = row0 + wm * 64 + f * 16 + rsub + r;
            dsc[f][r] = (row < M) ? dinv_s[row] : 0.0f;
        }
    #pragma unroll
    for (int f = 0; f < 4; ++f) {
        #pragma unroll
        for (int g = 0; g < 4; ++g) {
            int col = col0 + wn * 64 + g * 16 + fr;
            #pragma unroll
            for (int r = 0; r < 4; ++r) {
                int row = row0 + wm * 64 + f * 16 + rsub + r;
                if (row < M)
                    C[((size_t)(col >> LG) * M + row) * SW + (col & (SW - 1))] =
                        (_Float16)(acc[f][g][r] * dsc[f][r]);
            }
        }
    }
}

// ---------------------------------------------------------------------------
// XCD-sliced aggregation: slot-space, uint16 cs, single-fp16 output for
// MODE 0. MODE 1: fp32 scatter to orig rows.
// ---------------------------------------------------------------------------
template <int D, int MODE>
__global__ __launch_bounds__(256) void aggregate_slice_k(const _Float16* __restrict__ G,
                                                         const float* __restrict__ bias,
                                                         const float* __restrict__ dinv_s,
                                                         const int* __restrict__ rp,
                                                         const unsigned short* __restrict__ cs,
                                                         const int* __restrict__ perm,
                                                         _Float16* __restrict__ Yh,
                                                         float* __restrict__ Yf, int n) {
    constexpr int SLICE = (D == 256) ? 32 : 16;   // panel width
    constexpr int LPN = SLICE / 8;                // lanes per node (f16x8 each)
    constexpr int NPB = 256 / LPN;                // nodes per block

    int bid = blockIdx.x;
    int s = bid & 7;
    int slot = (bid >> 3) * NPB + threadIdx.x / LPN;
    if (slot >= n) return;
    int sub = threadIdx.x % LPN;
    int co = sub * 8;                             // within-panel col offset
    int col = s * SLICE + co;                     // global col (bias / out)

    const _Float16* Gs = G + (size_t)s * n * SLICE;   // this slice's panel

    float acc[8];
    {
        f16x8 t0 = *(const f16x8*)&Gs[(size_t)slot * SLICE + co];
        #pragma unroll
        for (int i = 0; i < 8; ++i) acc[i] = (float)t0[i];
    }

    int beg = rp[slot], end = rp[slot + 1];
    int j = beg;
    for (; j + 8 <= end; j += 8) {
        int cc[8];
        #pragma unroll
        for (int u = 0; u < 8; ++u) cc[u] = cs[j + u];
        f16x8 hv[8];
        #pragma unroll
        for (int u = 0; u < 8; ++u)
            hv[u] = *(const f16x8*)&Gs[(size_t)cc[u] * SLICE + co];
        #pragma unroll
        for (int u = 0; u < 8; ++u)
            #pragma unroll
            for (int i = 0; i < 8; ++i)
                acc[i] += (float)hv[u][i];
    }
    for (; j < end; ++j) {
        int c = cs[j];
        f16x8 a = *(const f16x8*)&Gs[(size_t)c * SLICE + co];
        #pragma unroll
        for (int i = 0; i < 8; ++i) acc[i] += (float)a[i];
    }

    float dv = dinv_s[slot];
    float4 b0 = *(const float4*)&bias[col];
    float4 b1 = *(const float4*)&bias[col + 4];
    float bb[8] = { b0.x, b0.y, b0.z, b0.w, b1.x, b1.y, b1.z, b1.w };

    if constexpr (MODE == 0) {
        f16x8 hh;
        #pragma unroll
        for (int i = 0; i < 8; ++i)
            hh[i] = (_Float16)fmaxf(dv * acc[i] + bb[i], 0.0f);
        size_t off = ((size_t)s * n + slot) * SLICE + co;   // slot-major out
        *(f16x8*)&Yh[off] = hh;
    } else {
        int v = perm[slot];                                 // orig node id
        float o[8];
        #pragma unroll
        for (int i = 0; i < 8; ++i) o[i] = dv * acc[i] + bb[i];
        *(float4*)&Yf[(size_t)v * D + col]     = make_float4(o[0], o[1], o[2], o[3]);
        *(float4*)&Yf[(size_t)v * D + col + 4] = make_float4(o[4], o[5], o[6], o[7]);
    }
}

// ---------------------------------------------------------------------------
extern "C" void kernel_launch(void* const* d_in, const int* in_sizes, int n_in,
                              void* d_out, int out_size, void* d_ws, size_t ws_size,
                              hipStream_t stream) {
    const float* qe  = (const float*)d_in[0];
    const float* obj = (const float*)d_in[1];
    const void*  edges = d_in[2];
    const float* W1 = (const float*)d_in[3];
    const float* b1 = (const float*)d_in[4];
    const float* W2 = (const float*)d_in[5];
    const float* b2 = (const float*)d_in[6];
    const float* W3 = (const float*)d_in[7];
    const float* b3 = (const float*)d_in[8];
    float* out = (float*)d_out;

    char* p = (char*)d_ws;
    _Float16* Xh   = (_Float16*)p; p += (size_t)NN * 256 * 2;   // 25.6 MB (slot-major)
    _Float16* H    = (_Float16*)p; p += (size_t)NN * 256 * 2;   // 25.6 MB (slot-major G)
    _Float16* B3   = (_Float16*)p; p += (size_t)256 * 512 * 2;  // 0.26 MB
    int*   dacc    = (int*)p;   p += (size_t)NN * 32 * 4;       // 6.4 MB (1/line)
    int*   cursorS = (int*)p;   p += (size_t)NN * 32 * 4;       // 6.4 MB (1/line)
    int*   deg     = (int*)p;   p += (size_t)NN * 4;
    int*   deg_s   = (int*)p;   p += (size_t)NN * 4;
    float* dinv_s  = (float*)p; p += (size_t)NN * 4;
    int*   rp      = (int*)p;   p += (size_t)(NN + 1) * 4;
    unsigned short* col_s = (unsigned short*)p; p += (size_t)NE * 2;
    int*   bh      = (int*)p;   p += (size_t)NBLK * 1024 * 4;   // 0.8 MB
    int*   tot     = (int*)p;   p += 1024 * 4;
    int*   bstart  = (int*)p;   p += 1024 * 4;
    int*   part    = (int*)p;   p += NBLK * 4;
    int*   perm    = (int*)p;   p += (size_t)NN * 4;
    int*   inv_perm= (int*)p;   p += (size_t)NN * 4;
    int*   flag    = (int*)p;   p += 4;

    zero_flag_k<<<1, 64, 0, stream>>>(flag);
    detect_k<<<4, 256, 0, stream>>>((const int*)edges, flag);
    init_k<<<(NN + 255) / 256, 256, 0, stream>>>(dacc, cursorS, NN);
    count_k<<<(NE + 255) / 256, 256, 0, stream>>>(edges, flag, dacc, NE);
    dcompact_k<<<(NN + 255) / 256, 256, 0, stream>>>(dacc, deg, NN);
    // degree-sorted renumbering
    bh_k<<<NBLK, 256, 0, stream>>>(deg, bh, NN);
    btot_k<<<1024, 256, 0, stream>>>(bh, tot, NBLK);
    hscan_k<<<1, 1024, 0, stream>>>(tot, bstart);
    bbase_k<<<1024, 256, 0, stream>>>(bh, bstart, NBLK);
    pscatter_k<<<NBLK, 256, 0, stream>>>(deg, bh, perm, inv_perm, NN);
    degs_k<<<NBLK, 256, 0, stream>>>(deg, perm, deg_s, dinv_s, NN);
    // rp over slot-space degrees
    ppart_k<<<NBLK, 256, 0, stream>>>(deg_s, part, NN);
    pscan1_k<<<1, 256, 0, stream>>>(part, NBLK);
    pwrite_k<<<NBLK, 256, 0, stream>>>(deg_s, part, rp, NN);
    // translated CSR (uint16 columns), strided cursors
    scatter_k<<<(NE + 255) / 256, 256, 0, stream>>>(edges, flag, inv_perm, rp, cursorS,
                                                    col_s, NE);
    // slot-major X0 (single fp16), 4 slots/wave
    hadamard_k<<<(NN / 16) + 1, 256, 0, stream>>>(
        (const float4*)qe, (const float4*)obj, perm, Xh, NN);

    int mblk = (NN + 127) / 128;                 // 391
    int gemmBigGrid = ((mblk + 7) / 8) * 16;     // 800 (pair-swizzled, 2 col blocks)
    int agg256Grid = ((NN + 63) / 64) * 8;       // 6256  (64 nodes/block, 4 lanes/node)
    int agg128Grid = ((NN + 127) / 128) * 8;     // 3128  (128 nodes/block, 2 lanes/node)

    // Layer 1
    wconv_k<<<256, 256, 0, stream>>>(W1, B3, 256);
    gemm_f16_k<2, 32><<<gemmBigGrid, 256, 0, stream>>>(Xh, B3, dinv_s, H, NN, 256);
    aggregate_slice_k<256, 0><<<agg256Grid, 256, 0, stream>>>(H, b1, dinv_s, rp, col_s, perm,
                                                              Xh, nullptr, NN);
    // Layer 2
    wconv_k<<<256, 256, 0, stream>>>(W2, B3, 256);
    gemm_f16_k<2, 32><<<gemmBigGrid, 256, 0, stream>>>(Xh, B3, dinv_s, H, NN, 256);
    aggregate_slice_k<256, 0><<<agg256Grid, 256, 0, stream>>>(H, b2, dinv_s, rp, col_s, perm,
                                                              Xh, nullptr, NN);
    // Layer 3
    wconv_k<<<128, 256, 0, stream>>>(W3, B3, 128);
    gemm_f16_k<1, 16><<<mblk, 256, 0, stream>>>(Xh, B3, dinv_s, H, NN, 128);
    aggregate_slice_k<128, 1><<<agg128Grid, 256, 0, stream>>>(H, b3, dinv_s, rp, col_s, perm,
                                                              nullptr, out, NN);
}

// Round 18
// 330.610 us; speedup vs baseline: 1.0070x; 1.0070x over previous
//
#include <hip/hip_runtime.h>
#include <cstdint>
#include <cstddef>

#define NN 50000
#define NE 800000
#define NBLK ((NN + 255) / 256)   // 196 node-chunks

typedef _Float16 f16x8 __attribute__((ext_vector_type(8)));
typedef _Float16 f16x4 __attribute__((ext_vector_type(4)));
typedef float f32x4 __attribute__((ext_vector_type(4)));

// ---------------------------------------------------------------------------
// Edge-index dtype robustness (int64 vs int32 canonicalization)
// ---------------------------------------------------------------------------
__device__ __forceinline__ int edge_at(const void* e, int is32, long long i) {
    return is32 ? ((const int*)e)[i] : (int)((const long long*)e)[i];
}

__global__ __launch_bounds__(64) void zero_flag_k(int* flag) {
    if (threadIdx.x == 0) *flag = 0;
}

__global__ __launch_bounds__(256) void detect_k(const int* __restrict__ w, int* __restrict__ flag) {
    int i = blockIdx.x * 256 + threadIdx.x;   // 0..1023
    if (i < 1024 && w[2 * i + 1] != 0) atomicOr(flag, 1);
}

// ---------------------------------------------------------------------------
// Atomic targets strided to ONE PER 128B LINE (32 ints) — r16 verified.
// ---------------------------------------------------------------------------
__global__ __launch_bounds__(256) void init_k(int* __restrict__ dacc,
                                              int* __restrict__ cursorS, int n) {
    int i = blockIdx.x * 256 + threadIdx.x;
    if (i < n) { dacc[(size_t)i * 32] = 1; cursorS[(size_t)i * 32] = 0; }
}

__global__ __launch_bounds__(256) void count_k(const void* __restrict__ edges,
                                               const int* __restrict__ flag,
                                               int* __restrict__ dacc, int e) {
    int i = blockIdx.x * 256 + threadIdx.x;
    if (i < e) {
        int is32 = *flag;
        atomicAdd(&dacc[(size_t)edge_at(edges, is32, i) * 32], 1);
    }
}

__global__ __launch_bounds__(256) void dcompact_k(const int* __restrict__ dacc,
                                                  int* __restrict__ deg, int n) {
    int i = blockIdx.x * 256 + threadIdx.x;
    if (i < n) deg[i] = dacc[(size_t)i * 32];
}

// ---------------------------------------------------------------------------
// Degree-sorted node permutation, contention-free 3-phase counting sort.
// ---------------------------------------------------------------------------
__global__ __launch_bounds__(256) void bh_k(const int* __restrict__ deg,
                                            int* __restrict__ bh, int n) {
    __shared__ int lh[1024];
    int t = threadIdx.x;
    for (int b = t; b < 1024; b += 256) lh[b] = 0;
    __syncthreads();
    int i = blockIdx.x * 256 + t;
    if (i < n) atomicAdd(&lh[min(deg[i], 1023)], 1);
    __syncthreads();
    for (int b = t; b < 1024; b += 256) bh[(size_t)blockIdx.x * 1024 + b] = lh[b];
}

__global__ __launch_bounds__(256) void btot_k(const int* __restrict__ bh,
                                              int* __restrict__ tot, int nb) {
    __shared__ int red[256];
    int b = blockIdx.x, t = threadIdx.x;
    int s = 0;
    for (int blk = t; blk < nb; blk += 256) s += bh[(size_t)blk * 1024 + b];
    red[t] = s;
    __syncthreads();
    for (int off = 128; off; off >>= 1) {
        if (t < off) red[t] += red[t + off];
        __syncthreads();
    }
    if (t == 0) tot[b] = red[0];
}

__global__ __launch_bounds__(1024) void hscan_k(const int* __restrict__ hist,
                                                int* __restrict__ bcur) {
    __shared__ int s[1024];
    int t = threadIdx.x;
    s[t] = hist[t];
    __syncthreads();
    for (int off = 1; off < 1024; off <<= 1) {
        int val = (t >= off) ? s[t - off] : 0;
        __syncthreads();
        s[t] += val;
        __syncthreads();
    }
    bcur[t] = (t == 0) ? 0 : s[t - 1];
}

__global__ __launch_bounds__(256) void bbase_k(int* __restrict__ bh,
                                               const int* __restrict__ bstart, int nb) {
    __shared__ int s[256];
    int b = blockIdx.x, t = threadIdx.x;
    int v = (t < nb) ? bh[(size_t)t * 1024 + b] : 0;
    s[t] = v;
    __syncthreads();
    for (int off = 1; off < 256; off <<= 1) {
        int x = (t >= off) ? s[t - off] : 0;
        __syncthreads();
        s[t] += x;
        __syncthreads();
    }
    int excl = (t == 0) ? 0 : s[t - 1];
    if (t < nb) bh[(size_t)t * 1024 + b] = bstart[b] + excl;
}

__global__ __launch_bounds__(256) void pscatter_k(const int* __restrict__ deg,
                                                  const int* __restrict__ bh,
                                                  int* __restrict__ perm,
                                                  int* __restrict__ inv_perm, int n) {
    __shared__ int lh[1024];
    int t = threadIdx.x;
    for (int b = t; b < 1024; b += 256) lh[b] = 0;
    __syncthreads();
    int i = blockIdx.x * 256 + t;
    int b = 0, r = 0;
    if (i < n) {
        b = min(deg[i], 1023);
        r = atomicAdd(&lh[b], 1);
    }
    __syncthreads();
    if (i < n) {
        int pos = bh[(size_t)blockIdx.x * 1024 + b] + r;
        perm[pos] = i;
        inv_perm[i] = pos;
    }
}

// slot-space degree + dinv
__global__ __launch_bounds__(256) void degs_k(const int* __restrict__ deg,
                                              const int* __restrict__ perm,
                                              int* __restrict__ deg_s,
                                              float* __restrict__ dinv_s, int n) {
    int i = blockIdx.x * 256 + threadIdx.x;
    if (i < n) {
        int d = deg[perm[i]];
        deg_s[i] = d;
        dinv_s[i] = rsqrtf((float)d);
    }
}

// ---------------------------------------------------------------------------
// Device-wide exclusive scan of (deg_s[i]-1) -> rp[0..n] (slot space)
// ---------------------------------------------------------------------------
__global__ __launch_bounds__(256) void ppart_k(const int* __restrict__ deg,
                                               int* __restrict__ part, int n) {
    __shared__ int red[256];
    int t = threadIdx.x;
    int i = blockIdx.x * 256 + t;
    red[t] = (i < n) ? deg[i] - 1 : 0;
    __syncthreads();
    for (int off = 128; off; off >>= 1) {
        if (t < off) red[t] += red[t + off];
        __syncthreads();
    }
    if (t == 0) part[blockIdx.x] = red[0];
}

__global__ __launch_bounds__(256) void pscan1_k(int* __restrict__ part, int nb) {
    __shared__ int s[256];
    int t = threadIdx.x;
    s[t] = (t < nb) ? part[t] : 0;
    __syncthreads();
    for (int off = 1; off < 256; off <<= 1) {
        int v = (t >= off) ? s[t - off] : 0;
        __syncthreads();
        s[t] += v;
        __syncthreads();
    }
    if (t < nb) part[t] = (t == 0) ? 0 : s[t - 1];
}

__global__ __launch_bounds__(256) void pwrite_k(const int* __restrict__ deg,
                                                const int* __restrict__ part,
                                                int* __restrict__ rp, int n) {
    __shared__ int s[256];
    int t = threadIdx.x;
    int i = blockIdx.x * 256 + t;
    int val = (i < n) ? deg[i] - 1 : 0;
    s[t] = val;
    __syncthreads();
    for (int off = 1; off < 256; off <<= 1) {
        int v = (t >= off) ? s[t - off] : 0;
        __syncthreads();
        s[t] += v;
        __syncthreads();
    }
    int incl = s[t];
    if (i < n) rp[i] = part[blockIdx.x] + incl - val;
    if (i == n - 1) rp[n] = part[blockIdx.x] + incl;
}

// CSR scatter with renumbering; strided (1-per-line) cursors; uint16 cols.
__global__ __launch_bounds__(256) void scatter_k(const void* __restrict__ edges,
                                                 const int* __restrict__ flag,
                                                 const int* __restrict__ inv_perm,
                                                 const int* __restrict__ rp,
                                                 int* __restrict__ cursorS,
                                                 unsigned short* __restrict__ col_s, int e) {
    int i = blockIdx.x * 256 + threadIdx.x;
    if (i < e) {
        int is32 = *flag;
        int r = inv_perm[edge_at(edges, is32, i)];
        int c = inv_perm[edge_at(edges, is32, (long long)NE + i)];
        int pos = rp[r] + atomicAdd(&cursorS[(size_t)r * 32], 1);
        col_s[pos] = (unsigned short)c;
    }
}

// ---------------------------------------------------------------------------
// Hadamard v3: fully sequential stream. Read qe/obj in original order
// (2x float4 per thread), write X0 row-major [node][256] fp16 (16B stores).
// The perm-scatter moves into GEMM-1's per-lane gload source (PERMA=1).
// ---------------------------------------------------------------------------
__global__ __launch_bounds__(256) void hadamard_k(const float4* __restrict__ a,
                                                  const float4* __restrict__ b,
                                                  _Float16* __restrict__ X0, int n8) {
    int i = blockIdx.x * 256 + threadIdx.x;   // each handles 8 fp32
    if (i >= n8) return;
    float4 x0 = a[2 * i], x1 = a[2 * i + 1];
    float4 y0 = b[2 * i], y1 = b[2 * i + 1];
    f16x8 h;
    h[0] = (_Float16)(x0.x * y0.x);
    h[1] = (_Float16)(x0.y * y0.y);
    h[2] = (_Float16)(x0.z * y0.z);
    h[3] = (_Float16)(x0.w * y0.w);
    h[4] = (_Float16)(x1.x * y1.x);
    h[5] = (_Float16)(x1.y * y1.y);
    h[6] = (_Float16)(x1.z * y1.z);
    h[7] = (_Float16)(x1.w * y1.w);
    *(f16x8*)&X0[(size_t)i * 8] = h;
}

// ---------------------------------------------------------------------------
// W convert: W[K=256][Nout] fp32 -> B3 [Nout][512] fp16, layout [Wh | Wl]
// ---------------------------------------------------------------------------
__global__ __launch_bounds__(256) void wconv_k(const float* __restrict__ W,
                                               _Float16* __restrict__ B3, int Nout) {
    int n = blockIdx.x;            // 0..Nout-1
    int k = threadIdx.x;           // 0..255
    float v = W[(size_t)k * Nout + n];
    _Float16 h = (_Float16)v;
    B3[(size_t)n * 512 + k]       = h;
    B3[(size_t)n * 512 + 256 + k] = (_Float16)(v - (float)h);
}

// ---------------------------------------------------------------------------
// fp16 MFMA GEMM over virtual K=512, double-buffered LDS, XOR chunk-swizzle.
// PERMA=0: A is slot-major panels (linear staging, aggregates' output).
// PERMA=1: A is row-major X0 in ORIGINAL node order; staging reads row
//          perm[slot] via per-lane gload source addresses (m104: global
//          source is per-lane even though LDS dest is wave-linear).
// Epilogue writes G = dinv_s[row] * (A@W).
// ---------------------------------------------------------------------------
__device__ __forceinline__ void gload_lds16(const void* g, void* l) {
    __builtin_amdgcn_global_load_lds(
        (const __attribute__((address_space(1))) void*)g,
        (__attribute__((address_space(3))) void*)l, 16, 0, 0);
}

template <int NBX, int SW, int PERMA>
__global__ __launch_bounds__(256) void gemm_f16_k(const _Float16* __restrict__ Ah,
                                                  const _Float16* __restrict__ B3,
                                                  const float* __restrict__ dinv_s,
                                                  const int* __restrict__ perm,
                                                  _Float16* __restrict__ C,
                                                  int M, int Nout) {
    __shared__ alignas(16) _Float16 sA[2][128 * 32];
    __shared__ alignas(16) _Float16 sB[2][128 * 32];
    constexpr int LG = (SW == 32) ? 5 : 4;
    constexpr int NST = 16;           // K = 512 / 32
    int mblk = (M + 127) >> 7;

    int pair, xb;
    if (NBX == 2) {
        int b = blockIdx.x;
        pair = (b >> 4) * 8 + (b & 7);     // row-panel id; pinned to XCD (b&7)
        xb   = (b >> 3) & 1;
        if (pair >= mblk) return;
    } else {
        pair = blockIdx.x;
        xb = 0;
    }

    int tid = threadIdx.x;
    int row0 = pair * 128, col0 = xb * 128;
    int wid = tid >> 6, lane = tid & 63;
    int wm = wid >> 1, wn = wid & 1;
    int fr = lane & 15;
    int kbc = lane >> 4;            // k chunk index 0..3 (8 fp16 each)

    int sr = lane >> 2;             // staging row within 16-row chunk
    int ke = (((lane & 3) ^ ((sr >> 1) & 3)) * 8);   // pre-swizzled source chunk

    // per-lane source rows for the two staging chunks (constant across steps)
    int arow_c[2], vsrc[2];
    #pragma unroll
    for (int c = 0; c < 2; ++c) {
        arow_c[c] = row0 + (wid * 2 + c) * 16 + sr;
        if (PERMA)
            vsrc[c] = (arow_c[c] < M) ? perm[arow_c[c]] : 0;
    }

    f32x4 acc[4][4] = {};

    auto STAGE = [&](int bsel, int s) {
        int p = s & 7;                    // A k-panel index
        #pragma unroll
        for (int c = 0; c < 2; ++c) {
            int ch = wid * 2 + c;         // 0..7
            if (arow_c[c] < M) {
                if (PERMA)
                    gload_lds16(&Ah[(size_t)vsrc[c] * 256 + p * 32 + ke], &sA[bsel][ch * 512]);
                else
                    gload_lds16(&Ah[((size_t)p * M + arow_c[c]) * 32 + ke], &sA[bsel][ch * 512]);
            }
            int r = ch * 16 + sr;
            gload_lds16(&B3[(size_t)(col0 + r) * 512 + s * 32 + ke], &sB[bsel][ch * 512]);
        }
    };

    STAGE(0, 0);
    __syncthreads();
    int cur = 0;

    for (int s = 0; s < NST; ++s) {
        if (s + 1 < NST) STAGE(cur ^ 1, s + 1);

        f16x8 af[4];
        #pragma unroll
        for (int f = 0; f < 4; ++f) {
            int rr = wm * 64 + f * 16 + fr;
            af[f] = *(const f16x8*)&sA[cur][rr * 32 + ((kbc ^ ((rr >> 1) & 3)) * 8)];
        }
        #pragma unroll
        for (int g = 0; g < 4; ++g) {
            int cc = wn * 64 + g * 16 + fr;
            f16x8 bf_ = *(const f16x8*)&sB[cur][cc * 32 + ((kbc ^ ((cc >> 1) & 3)) * 8)];
            #pragma unroll
            for (int f = 0; f < 4; ++f)
                acc[f][g] = __builtin_amdgcn_mfma_f32_16x16x32_f16(af[f], bf_, acc[f][g], 0, 0, 0);
        }

        __syncthreads();
        cur ^= 1;
    }

    int rsub = (lane >> 4) * 4;
    float dsc[4][4];
    #pragma unroll
    for (int f = 0; f < 4; ++f)
        #pragma unroll
        for (int r = 0; r < 4; ++r) {
            int row = row0 + wm * 64 + f * 16 + rsub + r;
            dsc[f][r] = (row < M) ? dinv_s[row] : 0.0f;
        }
    #pragma unroll
    for (int f = 0; f < 4; ++f) {
        #pragma unroll
        for (int g = 0; g < 4; ++g) {
            int col = col0 + wn * 64 + g * 16 + fr;
            #pragma unroll
            for (int r = 0; r < 4; ++r) {
                int row = row0 + wm * 64 + f * 16 + rsub + r;
                if (row < M)
                    C[((size_t)(col >> LG) * M + row) * SW + (col & (SW - 1))] =
                        (_Float16)(acc[f][g][r] * dsc[f][r]);
            }
        }
    }
}

// ---------------------------------------------------------------------------
// XCD-sliced aggregation: slot-space, uint16 cs, single-fp16 output for
// MODE 0 (slot-major panels). MODE 1: fp32 scatter to orig rows.
// ---------------------------------------------------------------------------
template <int D, int MODE>
__global__ __launch_bounds__(256) void aggregate_slice_k(const _Float16* __restrict__ G,
                                                         const float* __restrict__ bias,
                                                         const float* __restrict__ dinv_s,
                                                         const int* __restrict__ rp,
                                                         const unsigned short* __restrict__ cs,
                                                         const int* __restrict__ perm,
                                                         _Float16* __restrict__ Yh,
                                                         float* __restrict__ Yf, int n) {
    constexpr int SLICE = (D == 256) ? 32 : 16;   // panel width
    constexpr int LPN = SLICE / 8;                // lanes per node (f16x8 each)
    constexpr int NPB = 256 / LPN;                // nodes per block

    int bid = blockIdx.x;
    int s = bid & 7;
    int slot = (bid >> 3) * NPB + threadIdx.x / LPN;
    if (slot >= n) return;
    int sub = threadIdx.x % LPN;
    int co = sub * 8;                             // within-panel col offset
    int col = s * SLICE + co;                     // global col (bias / out)

    const _Float16* Gs = G + (size_t)s * n * SLICE;   // this slice's panel

    float acc[8];
    {
        f16x8 t0 = *(const f16x8*)&Gs[(size_t)slot * SLICE + co];
        #pragma unroll
        for (int i = 0; i < 8; ++i) acc[i] = (float)t0[i];
    }

    int beg = rp[slot], end = rp[slot + 1];
    int j = beg;
    for (; j + 8 <= end; j += 8) {
        int cc[8];
        #pragma unroll
        for (int u = 0; u < 8; ++u) cc[u] = cs[j + u];
        f16x8 hv[8];
        #pragma unroll
        for (int u = 0; u < 8; ++u)
            hv[u] = *(const f16x8*)&Gs[(size_t)cc[u] * SLICE + co];
        #pragma unroll
        for (int u = 0; u < 8; ++u)
            #pragma unroll
            for (int i = 0; i < 8; ++i)
                acc[i] += (float)hv[u][i];
    }
    for (; j < end; ++j) {
        int c = cs[j];
        f16x8 a = *(const f16x8*)&Gs[(size_t)c * SLICE + co];
        #pragma unroll
        for (int i = 0; i < 8; ++i) acc[i] += (float)a[i];
    }

    float dv = dinv_s[slot];
    float4 b0 = *(const float4*)&bias[col];
    float4 b1 = *(const float4*)&bias[col + 4];
    float bb[8] = { b0.x, b0.y, b0.z, b0.w, b1.x, b1.y, b1.z, b1.w };

    if constexpr (MODE == 0) {
        f16x8 hh;
        #pragma unroll
        for (int i = 0; i < 8; ++i)
            hh[i] = (_Float16)fmaxf(dv * acc[i] + bb[i], 0.0f);
        size_t off = ((size_t)s * n + slot) * SLICE + co;   // slot-major out
        *(f16x8*)&Yh[off] = hh;
    } else {
        int v = perm[slot];                                 // orig node id
        float o[8];
        #pragma unroll
        for (int i = 0; i < 8; ++i) o[i] = dv * acc[i] + bb[i];
        *(float4*)&Yf[(size_t)v * D + col]     = make_float4(o[0], o[1], o[2], o[3]);
        *(float4*)&Yf[(size_t)v * D + col + 4] = make_float4(o[4], o[5], o[6], o[7]);
    }
}

// ---------------------------------------------------------------------------
extern "C" void kernel_launch(void* const* d_in, const int* in_sizes, int n_in,
                              void* d_out, int out_size, void* d_ws, size_t ws_size,
                              hipStream_t stream) {
    const float* qe  = (const float*)d_in[0];
    const float* obj = (const float*)d_in[1];
    const void*  edges = d_in[2];
    const float* W1 = (const float*)d_in[3];
    const float* b1 = (const float*)d_in[4];
    const float* W2 = (const float*)d_in[5];
    const float* b2 = (const float*)d_in[6];
    const float* W3 = (const float*)d_in[7];
    const float* b3 = (const float*)d_in[8];
    float* out = (float*)d_out;

    char* p = (char*)d_ws;
    _Float16* Xh   = (_Float16*)p; p += (size_t)NN * 256 * 2;   // 25.6 MB (X0 row-major, then slot panels)
    _Float16* H    = (_Float16*)p; p += (size_t)NN * 256 * 2;   // 25.6 MB (slot-major G)
    _Float16* B3   = (_Float16*)p; p += (size_t)256 * 512 * 2;  // 0.26 MB
    int*   dacc    = (int*)p;   p += (size_t)NN * 32 * 4;       // 6.4 MB (1/line)
    int*   cursorS = (int*)p;   p += (size_t)NN * 32 * 4;       // 6.4 MB (1/line)
    int*   deg     = (int*)p;   p += (size_t)NN * 4;
    int*   deg_s   = (int*)p;   p += (size_t)NN * 4;
    float* dinv_s  = (float*)p; p += (size_t)NN * 4;
    int*   rp      = (int*)p;   p += (size_t)(NN + 1) * 4;
    unsigned short* col_s = (unsigned short*)p; p += (size_t)NE * 2;
    int*   bh      = (int*)p;   p += (size_t)NBLK * 1024 * 4;   // 0.8 MB
    int*   tot     = (int*)p;   p += 1024 * 4;
    int*   bstart  = (int*)p;   p += 1024 * 4;
    int*   part    = (int*)p;   p += NBLK * 4;
    int*   perm    = (int*)p;   p += (size_t)NN * 4;
    int*   inv_perm= (int*)p;   p += (size_t)NN * 4;
    int*   flag    = (int*)p;   p += 4;

    zero_flag_k<<<1, 64, 0, stream>>>(flag);
    detect_k<<<4, 256, 0, stream>>>((const int*)edges, flag);
    init_k<<<(NN + 255) / 256, 256, 0, stream>>>(dacc, cursorS, NN);
    count_k<<<(NE + 255) / 256, 256, 0, stream>>>(edges, flag, dacc, NE);
    dcompact_k<<<(NN + 255) / 256, 256, 0, stream>>>(dacc, deg, NN);
    // degree-sorted renumbering
    bh_k<<<NBLK, 256, 0, stream>>>(deg, bh, NN);
    btot_k<<<1024, 256, 0, stream>>>(bh, tot, NBLK);
    hscan_k<<<1, 1024, 0, stream>>>(tot, bstart);
    bbase_k<<<1024, 256, 0, stream>>>(bh, bstart, NBLK);
    pscatter_k<<<NBLK, 256, 0, stream>>>(deg, bh, perm, inv_perm, NN);
    degs_k<<<NBLK, 256, 0, stream>>>(deg, perm, deg_s, dinv_s, NN);
    // rp over slot-space degrees
    ppart_k<<<NBLK, 256, 0, stream>>>(deg_s, part, NN);
    pscan1_k<<<1, 256, 0, stream>>>(part, NBLK);
    pwrite_k<<<NBLK, 256, 0, stream>>>(deg_s, part, rp, NN);
    // translated CSR (uint16 columns), strided cursors
    scatter_k<<<(NE + 255) / 256, 256, 0, stream>>>(edges, flag, inv_perm, rp, cursorS,
                                                    col_s, NE);
    // X0 = qe*obj, sequential stream, row-major original order
    hadamard_k<<<(NN * 32 + 255) / 256, 256, 0, stream>>>(
        (const float4*)qe, (const float4*)obj, Xh, NN * 32);

    int mblk = (NN + 127) / 128;                 // 391
    int gemmBigGrid = ((mblk + 7) / 8) * 16;     // 800 (pair-swizzled, 2 col blocks)
    int agg256Grid = ((NN + 63) / 64) * 8;       // 6256  (64 nodes/block, 4 lanes/node)
    int agg128Grid = ((NN + 127) / 128) * 8;     // 3128  (128 nodes/block, 2 lanes/node)

    // Layer 1 (perm-indirect A staging from row-major X0)
    wconv_k<<<256, 256, 0, stream>>>(W1, B3, 256);
    gemm_f16_k<2, 32, 1><<<gemmBigGrid, 256, 0, stream>>>(Xh, B3, dinv_s, perm, H, NN, 256);
    aggregate_slice_k<256, 0><<<agg256Grid, 256, 0, stream>>>(H, b1, dinv_s, rp, col_s, perm,
                                                              Xh, nullptr, NN);
    // Layer 2 (linear panel staging)
    wconv_k<<<256, 256, 0, stream>>>(W2, B3, 256);
    gemm_f16_k<2, 32, 0><<<gemmBigGrid, 256, 0, stream>>>(Xh, B3, dinv_s, perm, H, NN, 256);
    aggregate_slice_k<256, 0><<<agg256Grid, 256, 0, stream>>>(H, b2, dinv_s, rp, col_s, perm,
                                                              Xh, nullptr, NN);
    // Layer 3
    wconv_k<<<128, 256, 0, stream>>>(W3, B3, 128);
    gemm_f16_k<1, 16, 0><<<mblk, 256, 0, stream>>>(Xh, B3, dinv_s, perm, H, NN, 128);
    aggregate_slice_k<128, 1><<<agg128Grid, 256, 0, stream>>>(H, b3, dinv_s, rp, col_s, perm,
                                                              nullptr, out, NN);
}

// Round 19
// 310.055 us; speedup vs baseline: 1.0737x; 1.0663x over previous
//
#include <hip/hip_runtime.h>
#include <cstdint>
#include <cstddef>

#define NN 50000
#define NE 800000
#define NBLK ((NN + 255) / 256)   // 196 node-chunks

typedef _Float16 f16x8 __attribute__((ext_vector_type(8)));
typedef _Float16 f16x4 __attribute__((ext_vector_type(4)));
typedef float f32x4 __attribute__((ext_vector_type(4)));

// ---------------------------------------------------------------------------
// Edge-index dtype robustness (int64 vs int32 canonicalization)
// ---------------------------------------------------------------------------
__device__ __forceinline__ int edge_at(const void* e, int is32, long long i) {
    return is32 ? ((const int*)e)[i] : (int)((const long long*)e)[i];
}

__global__ __launch_bounds__(64) void zero_flag_k(int* flag) {
    if (threadIdx.x == 0) *flag = 0;
}

__global__ __launch_bounds__(256) void detect_k(const int* __restrict__ w, int* __restrict__ flag) {
    int i = blockIdx.x * 256 + threadIdx.x;   // 0..1023
    if (i < 1024 && w[2 * i + 1] != 0) atomicOr(flag, 1);
}

// ---------------------------------------------------------------------------
// Degree count with RANK CAPTURE: the atomicAdd's return value IS the edge's
// rank within its destination row (1-based; dacc init 1 = self-loop).
// dacc strided 1-per-128B-line (r16: kills same-line RMW serialization).
// The CSR scatter then needs NO atomic (r18: scatter's RMW chain + cursorS
// L2 thrash was ~44 us).
// ---------------------------------------------------------------------------
__global__ __launch_bounds__(256) void init_k(int* __restrict__ dacc, int n) {
    int i = blockIdx.x * 256 + threadIdx.x;
    if (i < n) dacc[(size_t)i * 32] = 1;
}

__global__ __launch_bounds__(256) void count_k(const void* __restrict__ edges,
                                               const int* __restrict__ flag,
                                               int* __restrict__ dacc,
                                               int* __restrict__ rank, int e) {
    int i = blockIdx.x * 256 + threadIdx.x;
    if (i < e) {
        int is32 = *flag;
        rank[i] = atomicAdd(&dacc[(size_t)edge_at(edges, is32, i) * 32], 1);
    }
}

__global__ __launch_bounds__(256) void dcompact_k(const int* __restrict__ dacc,
                                                  int* __restrict__ deg, int n) {
    int i = blockIdx.x * 256 + threadIdx.x;
    if (i < n) deg[i] = dacc[(size_t)i * 32];
}

// ---------------------------------------------------------------------------
// Degree-sorted node permutation, contention-free 3-phase counting sort.
// ---------------------------------------------------------------------------
__global__ __launch_bounds__(256) void bh_k(const int* __restrict__ deg,
                                            int* __restrict__ bh, int n) {
    __shared__ int lh[1024];
    int t = threadIdx.x;
    for (int b = t; b < 1024; b += 256) lh[b] = 0;
    __syncthreads();
    int i = blockIdx.x * 256 + t;
    if (i < n) atomicAdd(&lh[min(deg[i], 1023)], 1);
    __syncthreads();
    for (int b = t; b < 1024; b += 256) bh[(size_t)blockIdx.x * 1024 + b] = lh[b];
}

__global__ __launch_bounds__(256) void btot_k(const int* __restrict__ bh,
                                              int* __restrict__ tot, int nb) {
    __shared__ int red[256];
    int b = blockIdx.x, t = threadIdx.x;
    int s = 0;
    for (int blk = t; blk < nb; blk += 256) s += bh[(size_t)blk * 1024 + b];
    red[t] = s;
    __syncthreads();
    for (int off = 128; off; off >>= 1) {
        if (t < off) red[t] += red[t + off];
        __syncthreads();
    }
    if (t == 0) tot[b] = red[0];
}

__global__ __launch_bounds__(1024) void hscan_k(const int* __restrict__ hist,
                                                int* __restrict__ bcur) {
    __shared__ int s[1024];
    int t = threadIdx.x;
    s[t] = hist[t];
    __syncthreads();
    for (int off = 1; off < 1024; off <<= 1) {
        int val = (t >= off) ? s[t - off] : 0;
        __syncthreads();
        s[t] += val;
        __syncthreads();
    }
    bcur[t] = (t == 0) ? 0 : s[t - 1];
}

__global__ __launch_bounds__(256) void bbase_k(int* __restrict__ bh,
                                               const int* __restrict__ bstart, int nb) {
    __shared__ int s[256];
    int b = blockIdx.x, t = threadIdx.x;
    int v = (t < nb) ? bh[(size_t)t * 1024 + b] : 0;
    s[t] = v;
    __syncthreads();
    for (int off = 1; off < 256; off <<= 1) {
        int x = (t >= off) ? s[t - off] : 0;
        __syncthreads();
        s[t] += x;
        __syncthreads();
    }
    int excl = (t == 0) ? 0 : s[t - 1];
    if (t < nb) bh[(size_t)t * 1024 + b] = bstart[b] + excl;
}

__global__ __launch_bounds__(256) void pscatter_k(const int* __restrict__ deg,
                                                  const int* __restrict__ bh,
                                                  int* __restrict__ perm,
                                                  int* __restrict__ inv_perm, int n) {
    __shared__ int lh[1024];
    int t = threadIdx.x;
    for (int b = t; b < 1024; b += 256) lh[b] = 0;
    __syncthreads();
    int i = blockIdx.x * 256 + t;
    int b = 0, r = 0;
    if (i < n) {
        b = min(deg[i], 1023);
        r = atomicAdd(&lh[b], 1);
    }
    __syncthreads();
    if (i < n) {
        int pos = bh[(size_t)blockIdx.x * 1024 + b] + r;
        perm[pos] = i;
        inv_perm[i] = pos;
    }
}

// slot-space degree + dinv
__global__ __launch_bounds__(256) void degs_k(const int* __restrict__ deg,
                                              const int* __restrict__ perm,
                                              int* __restrict__ deg_s,
                                              float* __restrict__ dinv_s, int n) {
    int i = blockIdx.x * 256 + threadIdx.x;
    if (i < n) {
        int d = deg[perm[i]];
        deg_s[i] = d;
        dinv_s[i] = rsqrtf((float)d);
    }
}

// ---------------------------------------------------------------------------
// Device-wide exclusive scan of (deg_s[i]-1) -> rp[0..n] (slot space)
// ---------------------------------------------------------------------------
__global__ __launch_bounds__(256) void ppart_k(const int* __restrict__ deg,
                                               int* __restrict__ part, int n) {
    __shared__ int red[256];
    int t = threadIdx.x;
    int i = blockIdx.x * 256 + t;
    red[t] = (i < n) ? deg[i] - 1 : 0;
    __syncthreads();
    for (int off = 128; off; off >>= 1) {
        if (t < off) red[t] += red[t + off];
        __syncthreads();
    }
    if (t == 0) part[blockIdx.x] = red[0];
}

__global__ __launch_bounds__(256) void pscan1_k(int* __restrict__ part, int nb) {
    __shared__ int s[256];
    int t = threadIdx.x;
    s[t] = (t < nb) ? part[t] : 0;
    __syncthreads();
    for (int off = 1; off < 256; off <<= 1) {
        int v = (t >= off) ? s[t - off] : 0;
        __syncthreads();
        s[t] += v;
        __syncthreads();
    }
    if (t < nb) part[t] = (t == 0) ? 0 : s[t - 1];
}

__global__ __launch_bounds__(256) void pwrite_k(const int* __restrict__ deg,
                                                const int* __restrict__ part,
                                                int* __restrict__ rp, int n) {
    __shared__ int s[256];
    int t = threadIdx.x;
    int i = blockIdx.x * 256 + t;
    int val = (i < n) ? deg[i] - 1 : 0;
    s[t] = val;
    __syncthreads();
    for (int off = 1; off < 256; off <<= 1) {
        int v = (t >= off) ? s[t - off] : 0;
        __syncthreads();
        s[t] += v;
        __syncthreads();
    }
    int incl = s[t];
    if (i < n) rp[i] = part[blockIdx.x] + incl - val;
    if (i == n - 1) rp[n] = part[blockIdx.x] + incl;
}

// CSR scatter, ATOMIC-FREE: pos = rp[slot(r)] + rank[i]-1.
__global__ __launch_bounds__(256) void scatter_k(const void* __restrict__ edges,
                                                 const int* __restrict__ flag,
                                                 const int* __restrict__ inv_perm,
                                                 const int* __restrict__ rp,
                                                 const int* __restrict__ rank,
                                                 unsigned short* __restrict__ col_s, int e) {
    int i = blockIdx.x * 256 + threadIdx.x;
    if (i < e) {
        int is32 = *flag;
        int r = inv_perm[edge_at(edges, is32, i)];
        int c = inv_perm[edge_at(edges, is32, (long long)NE + i)];
        int pos = rp[r] + rank[i] - 1;
        col_s[pos] = (unsigned short)c;
    }
}

// ---------------------------------------------------------------------------
// Hadamard: fully sequential stream. Read qe/obj in original order,
// write X0 row-major [node][256] fp16 (16B stores).
// ---------------------------------------------------------------------------
__global__ __launch_bounds__(256) void hadamard_k(const float4* __restrict__ a,
                                                  const float4* __restrict__ b,
                                                  _Float16* __restrict__ X0, int n8) {
    int i = blockIdx.x * 256 + threadIdx.x;   // each handles 8 fp32
    if (i >= n8) return;
    float4 x0 = a[2 * i], x1 = a[2 * i + 1];
    float4 y0 = b[2 * i], y1 = b[2 * i + 1];
    f16x8 h;
    h[0] = (_Float16)(x0.x * y0.x);
    h[1] = (_Float16)(x0.y * y0.y);
    h[2] = (_Float16)(x0.z * y0.z);
    h[3] = (_Float16)(x0.w * y0.w);
    h[4] = (_Float16)(x1.x * y1.x);
    h[5] = (_Float16)(x1.y * y1.y);
    h[6] = (_Float16)(x1.z * y1.z);
    h[7] = (_Float16)(x1.w * y1.w);
    *(f16x8*)&X0[(size_t)i * 8] = h;
}

// ---------------------------------------------------------------------------
// W convert: W[K=256][Nout] fp32 -> B3 [Nout][512] fp16, layout [Wh | Wl]
// ---------------------------------------------------------------------------
__global__ __launch_bounds__(256) void wconv_k(const float* __restrict__ W,
                                               _Float16* __restrict__ B3, int Nout) {
    int n = blockIdx.x;            // 0..Nout-1
    int k = threadIdx.x;           // 0..255
    float v = W[(size_t)k * Nout + n];
    _Float16 h = (_Float16)v;
    B3[(size_t)n * 512 + k]       = h;
    B3[(size_t)n * 512 + 256 + k] = (_Float16)(v - (float)h);
}

// ---------------------------------------------------------------------------
// fp16 MFMA GEMM over virtual K=512, double-buffered LDS, XOR chunk-swizzle.
// PERMA=0: A is slot-major panels (linear staging).
// PERMA=1: A is row-major X0 in original order; staging reads row perm[slot]
//          via per-lane gload source addresses.
// Epilogue writes G = dinv_s[row] * (A@W).
// ---------------------------------------------------------------------------
__device__ __forceinline__ void gload_lds16(const void* g, void* l) {
    __builtin_amdgcn_global_load_lds(
        (const __attribute__((address_space(1))) void*)g,
        (__attribute__((address_space(3))) void*)l, 16, 0, 0);
}

template <int NBX, int SW, int PERMA>
__global__ __launch_bounds__(256) void gemm_f16_k(const _Float16* __restrict__ Ah,
                                                  const _Float16* __restrict__ B3,
                                                  const float* __restrict__ dinv_s,
                                                  const int* __restrict__ perm,
                                                  _Float16* __restrict__ C,
                                                  int M, int Nout) {
    __shared__ alignas(16) _Float16 sA[2][128 * 32];
    __shared__ alignas(16) _Float16 sB[2][128 * 32];
    constexpr int LG = (SW == 32) ? 5 : 4;
    constexpr int NST = 16;           // K = 512 / 32
    int mblk = (M + 127) >> 7;

    int pair, xb;
    if (NBX == 2) {
        int b = blockIdx.x;
        pair = (b >> 4) * 8 + (b & 7);     // row-panel id; pinned to XCD (b&7)
        xb   = (b >> 3) & 1;
        if (pair >= mblk) return;
    } else {
        pair = blockIdx.x;
        xb = 0;
    }

    int tid = threadIdx.x;
    int row0 = pair * 128, col0 = xb * 128;
    int wid = tid >> 6, lane = tid & 63;
    int wm = wid >> 1, wn = wid & 1;
    int fr = lane & 15;
    int kbc = lane >> 4;            // k chunk index 0..3 (8 fp16 each)

    int sr = lane >> 2;             // staging row within 16-row chunk
    int ke = (((lane & 3) ^ ((sr >> 1) & 3)) * 8);   // pre-swizzled source chunk

    int arow_c[2], vsrc[2];
    #pragma unroll
    for (int c = 0; c < 2; ++c) {
        arow_c[c] = row0 + (wid * 2 + c) * 16 + sr;
        if (PERMA)
            vsrc[c] = (arow_c[c] < M) ? perm[arow_c[c]] : 0;
    }

    f32x4 acc[4][4] = {};

    auto STAGE = [&](int bsel, int s) {
        int p = s & 7;                    // A k-panel index
        #pragma unroll
        for (int c = 0; c < 2; ++c) {
            int ch = wid * 2 + c;         // 0..7
            if (arow_c[c] < M) {
                if (PERMA)
                    gload_lds16(&Ah[(size_t)vsrc[c] * 256 + p * 32 + ke], &sA[bsel][ch * 512]);
                else
                    gload_lds16(&Ah[((size_t)p * M + arow_c[c]) * 32 + ke], &sA[bsel][ch * 512]);
            }
            int r = ch * 16 + sr;
            gload_lds16(&B3[(size_t)(col0 + r) * 512 + s * 32 + ke], &sB[bsel][ch * 512]);
        }
    };

    STAGE(0, 0);
    __syncthreads();
    int cur = 0;

    for (int s = 0; s < NST; ++s) {
        if (s + 1 < NST) STAGE(cur ^ 1, s + 1);

        f16x8 af[4];
        #pragma unroll
        for (int f = 0; f < 4; ++f) {
            int rr = wm * 64 + f * 16 + fr;
            af[f] = *(const f16x8*)&sA[cur][rr * 32 + ((kbc ^ ((rr >> 1) & 3)) * 8)];
        }
        #pragma unroll
        for (int g = 0; g < 4; ++g) {
            int cc = wn * 64 + g * 16 + fr;
            f16x8 bf_ = *(const f16x8*)&sB[cur][cc * 32 + ((kbc ^ ((cc >> 1) & 3)) * 8)];
            #pragma unroll
            for (int f = 0; f < 4; ++f)
                acc[f][g] = __builtin_amdgcn_mfma_f32_16x16x32_f16(af[f], bf_, acc[f][g], 0, 0, 0);
        }

        __syncthreads();
        cur ^= 1;
    }

    int rsub = (lane >> 4) * 4;
    float dsc[4][4];
    #pragma unroll
    for (int f = 0; f < 4; ++f)
        #pragma unroll
        for (int r = 0; r < 4; ++r) {
            int row = row0 + wm * 64 + f * 16 + rsub + r;
            dsc[f][r] = (row < M) ? dinv_s[row] : 0.0f;
        }
    #pragma unroll
    for (int f = 0; f < 4; ++f) {
        #pragma unroll
        for (int g = 0; g < 4; ++g) {
            int col = col0 + wn * 64 + g * 16 + fr;
            #pragma unroll
            for (int r = 0; r < 4; ++r) {
                int row = row0 + wm * 64 + f * 16 + rsub + r;
                if (row < M)
                    C[((size_t)(col >> LG) * M + row) * SW + (col & (SW - 1))] =
                        (_Float16)(acc[f][g][r] * dsc[f][r]);
            }
        }
    }
}

// ---------------------------------------------------------------------------
// XCD-sliced aggregation: slot-space, uint16 cs, single-fp16 output for
// MODE 0 (slot-major panels). MODE 1: fp32 scatter to orig rows.
// ---------------------------------------------------------------------------
template <int D, int MODE>
__global__ __launch_bounds__(256) void aggregate_slice_k(const _Float16* __restrict__ G,
                                                         const float* __restrict__ bias,
                                                         const float* __restrict__ dinv_s,
                                                         const int* __restrict__ rp,
                                                         const unsigned short* __restrict__ cs,
                                                         const int* __restrict__ perm,
                                                         _Float16* __restrict__ Yh,
                                                         float* __restrict__ Yf, int n) {
    constexpr int SLICE = (D == 256) ? 32 : 16;   // panel width
    constexpr int LPN = SLICE / 8;                // lanes per node (f16x8 each)
    constexpr int NPB = 256 / LPN;                // nodes per block

    int bid = blockIdx.x;
    int s = bid & 7;
    int slot = (bid >> 3) * NPB + threadIdx.x / LPN;
    if (slot >= n) return;
    int sub = threadIdx.x % LPN;
    int co = sub * 8;                             // within-panel col offset
    int col = s * SLICE + co;                     // global col (bias / out)

    const _Float16* Gs = G + (size_t)s * n * SLICE;   // this slice's panel

    float acc[8];
    {
        f16x8 t0 = *(const f16x8*)&Gs[(size_t)slot * SLICE + co];
        #pragma unroll
        for (int i = 0; i < 8; ++i) acc[i] = (float)t0[i];
    }

    int beg = rp[slot], end = rp[slot + 1];
    int j = beg;
    for (; j + 8 <= end; j += 8) {
        int cc[8];
        #pragma unroll
        for (int u = 0; u < 8; ++u) cc[u] = cs[j + u];
        f16x8 hv[8];
        #pragma unroll
        for (int u = 0; u < 8; ++u)
            hv[u] = *(const f16x8*)&Gs[(size_t)cc[u] * SLICE + co];
        #pragma unroll
        for (int u = 0; u < 8; ++u)
            #pragma unroll
            for (int i = 0; i < 8; ++i)
                acc[i] += (float)hv[u][i];
    }
    for (; j < end; ++j) {
        int c = cs[j];
        f16x8 a = *(const f16x8*)&Gs[(size_t)c * SLICE + co];
        #pragma unroll
        for (int i = 0; i < 8; ++i) acc[i] += (float)a[i];
    }

    float dv = dinv_s[slot];
    float4 b0 = *(const float4*)&bias[col];
    float4 b1 = *(const float4*)&bias[col + 4];
    float bb[8] = { b0.x, b0.y, b0.z, b0.w, b1.x, b1.y, b1.z, b1.w };

    if constexpr (MODE == 0) {
        f16x8 hh;
        #pragma unroll
        for (int i = 0; i < 8; ++i)
            hh[i] = (_Float16)fmaxf(dv * acc[i] + bb[i], 0.0f);
        size_t off = ((size_t)s * n + slot) * SLICE + co;   // slot-major out
        *(f16x8*)&Yh[off] = hh;
    } else {
        int v = perm[slot];                                 // orig node id
        float o[8];
        #pragma unroll
        for (int i = 0; i < 8; ++i) o[i] = dv * acc[i] + bb[i];
        *(float4*)&Yf[(size_t)v * D + col]     = make_float4(o[0], o[1], o[2], o[3]);
        *(float4*)&Yf[(size_t)v * D + col + 4] = make_float4(o[4], o[5], o[6], o[7]);
    }
}

// ---------------------------------------------------------------------------
extern "C" void kernel_launch(void* const* d_in, const int* in_sizes, int n_in,
                              void* d_out, int out_size, void* d_ws, size_t ws_size,
                              hipStream_t stream) {
    const float* qe  = (const float*)d_in[0];
    const float* obj = (const float*)d_in[1];
    const void*  edges = d_in[2];
    const float* W1 = (const float*)d_in[3];
    const float* b1 = (const float*)d_in[4];
    const float* W2 = (const float*)d_in[5];
    const float* b2 = (const float*)d_in[6];
    const float* W3 = (const float*)d_in[7];
    const float* b3 = (const float*)d_in[8];
    float* out = (float*)d_out;

    char* p = (char*)d_ws;
    _Float16* Xh   = (_Float16*)p; p += (size_t)NN * 256 * 2;   // 25.6 MB
    _Float16* H    = (_Float16*)p; p += (size_t)NN * 256 * 2;   // 25.6 MB
    _Float16* B3   = (_Float16*)p; p += (size_t)256 * 512 * 2;  // 0.26 MB
    int*   dacc    = (int*)p;   p += (size_t)NN * 32 * 4;       // 6.4 MB (1/line)
    int*   rank    = (int*)p;   p += (size_t)NE * 4;            // 3.2 MB
    int*   deg     = (int*)p;   p += (size_t)NN * 4;
    int*   deg_s   = (int*)p;   p += (size_t)NN * 4;
    float* dinv_s  = (float*)p; p += (size_t)NN * 4;
    int*   rp      = (int*)p;   p += (size_t)(NN + 1) * 4;
    unsigned short* col_s = (unsigned short*)p; p += (size_t)NE * 2;
    int*   bh      = (int*)p;   p += (size_t)NBLK * 1024 * 4;   // 0.8 MB
    int*   tot     = (int*)p;   p += 1024 * 4;
    int*   bstart  = (int*)p;   p += 1024 * 4;
    int*   part    = (int*)p;   p += NBLK * 4;
    int*   perm    = (int*)p;   p += (size_t)NN * 4;
    int*   inv_perm= (int*)p;   p += (size_t)NN * 4;
    int*   flag    = (int*)p;   p += 4;

    zero_flag_k<<<1, 64, 0, stream>>>(flag);
    detect_k<<<4, 256, 0, stream>>>((const int*)edges, flag);
    init_k<<<(NN + 255) / 256, 256, 0, stream>>>(dacc, NN);
    count_k<<<(NE + 255) / 256, 256, 0, stream>>>(edges, flag, dacc, rank, NE);
    dcompact_k<<<(NN + 255) / 256, 256, 0, stream>>>(dacc, deg, NN);
    // degree-sorted renumbering
    bh_k<<<NBLK, 256, 0, stream>>>(deg, bh, NN);
    btot_k<<<1024, 256, 0, stream>>>(bh, tot, NBLK);
    hscan_k<<<1, 1024, 0, stream>>>(tot, bstart);
    bbase_k<<<1024, 256, 0, stream>>>(bh, bstart, NBLK);
    pscatter_k<<<NBLK, 256, 0, stream>>>(deg, bh, perm, inv_perm, NN);
    degs_k<<<NBLK, 256, 0, stream>>>(deg, perm, deg_s, dinv_s, NN);
    // rp over slot-space degrees
    ppart_k<<<NBLK, 256, 0, stream>>>(deg_s, part, NN);
    pscan1_k<<<1, 256, 0, stream>>>(part, NBLK);
    pwrite_k<<<NBLK, 256, 0, stream>>>(deg_s, part, rp, NN);
    // translated CSR (uint16 columns), atomic-free via captured ranks
    scatter_k<<<(NE + 255) / 256, 256, 0, stream>>>(edges, flag, inv_perm, rp, rank,
                                                    col_s, NE);
    // X0 = qe*obj, sequential stream, row-major original order
    hadamard_k<<<(NN * 32 + 255) / 256, 256, 0, stream>>>(
        (const float4*)qe, (const float4*)obj, Xh, NN * 32);

    int mblk = (NN + 127) / 128;                 // 391
    int gemmBigGrid = ((mblk + 7) / 8) * 16;     // 800 (pair-swizzled, 2 col blocks)
    int agg256Grid = ((NN + 63) / 64) * 8;       // 6256
    int agg128Grid = ((NN + 127) / 128) * 8;     // 3128

    // Layer 1 (perm-indirect A staging from row-major X0)
    wconv_k<<<256, 256, 0, stream>>>(W1, B3, 256);
    gemm_f16_k<2, 32, 1><<<gemmBigGrid, 256, 0, stream>>>(Xh, B3, dinv_s, perm, H, NN, 256);
    aggregate_slice_k<256, 0><<<agg256Grid, 256, 0, stream>>>(H, b1, dinv_s, rp, col_s, perm,
                                                              Xh, nullptr, NN);
    // Layer 2 (linear panel staging)
    wconv_k<<<256, 256, 0, stream>>>(W2, B3, 256);
    gemm_f16_k<2, 32, 0><<<gemmBigGrid, 256, 0, stream>>>(Xh, B3, dinv_s, perm, H, NN, 256);
    aggregate_slice_k<256, 0><<<agg256Grid, 256, 0, stream>>>(H, b2, dinv_s, rp, col_s, perm,
                                                              Xh, nullptr, NN);
    // Layer 3
    wconv_k<<<128, 256, 0, stream>>>(W3, B3, 128);
    gemm_f16_k<1, 16, 0><<<mblk, 256, 0, stream>>>(Xh, B3, dinv_s, perm, H, NN, 128);
    aggregate_slice_k<128, 1><<<agg128Grid, 256, 0, stream>>>(H, b3, dinv_s, rp, col_s, perm,
                                                              nullptr, out, NN);
}

// Round 20
// 308.295 us; speedup vs baseline: 1.0799x; 1.0057x over previous
//
#include <hip/hip_runtime.h>
#include <cstdint>
#include <cstddef>

#define NN 50000
#define NE 800000
#define NBLK ((NN + 255) / 256)   // 196 node-chunks

typedef _Float16 f16x8 __attribute__((ext_vector_type(8)));
typedef _Float16 f16x4 __attribute__((ext_vector_type(4)));
typedef float f32x4 __attribute__((ext_vector_type(4)));

// ---------------------------------------------------------------------------
// Edge-index dtype robustness (int64 vs int32 canonicalization)
// ---------------------------------------------------------------------------
__device__ __forceinline__ int edge_at(const void* e, int is32, long long i) {
    return is32 ? ((const int*)e)[i] : (int)((const long long*)e)[i];
}

__global__ __launch_bounds__(64) void zero_flag_k(int* flag) {
    if (threadIdx.x == 0) *flag = 0;
}

__global__ __launch_bounds__(256) void detect_k(const int* __restrict__ w, int* __restrict__ flag) {
    int i = blockIdx.x * 256 + threadIdx.x;   // 0..1023
    if (i < 1024 && w[2 * i + 1] != 0) atomicOr(flag, 1);
}

// ---------------------------------------------------------------------------
// Degree count with RANK CAPTURE (r19: atomic-free CSR scatter).
// dacc strided 1-per-128B-line (r16: kills same-line RMW serialization).
// ---------------------------------------------------------------------------
__global__ __launch_bounds__(256) void init_k(int* __restrict__ dacc, int n) {
    int i = blockIdx.x * 256 + threadIdx.x;
    if (i < n) dacc[(size_t)i * 32] = 1;
}

__global__ __launch_bounds__(256) void count_k(const void* __restrict__ edges,
                                               const int* __restrict__ flag,
                                               int* __restrict__ dacc,
                                               int* __restrict__ rank, int e) {
    int i = blockIdx.x * 256 + threadIdx.x;
    if (i < e) {
        int is32 = *flag;
        rank[i] = atomicAdd(&dacc[(size_t)edge_at(edges, is32, i) * 32], 1);
    }
}

__global__ __launch_bounds__(256) void dcompact_k(const int* __restrict__ dacc,
                                                  int* __restrict__ deg, int n) {
    int i = blockIdx.x * 256 + threadIdx.x;
    if (i < n) deg[i] = dacc[(size_t)i * 32];
}

// ---------------------------------------------------------------------------
// Degree-sorted node permutation, contention-free 3-phase counting sort.
// ---------------------------------------------------------------------------
__global__ __launch_bounds__(256) void bh_k(const int* __restrict__ deg,
                                            int* __restrict__ bh, int n) {
    __shared__ int lh[1024];
    int t = threadIdx.x;
    for (int b = t; b < 1024; b += 256) lh[b] = 0;
    __syncthreads();
    int i = blockIdx.x * 256 + t;
    if (i < n) atomicAdd(&lh[min(deg[i], 1023)], 1);
    __syncthreads();
    for (int b = t; b < 1024; b += 256) bh[(size_t)blockIdx.x * 1024 + b] = lh[b];
}

__global__ __launch_bounds__(256) void btot_k(const int* __restrict__ bh,
                                              int* __restrict__ tot, int nb) {
    __shared__ int red[256];
    int b = blockIdx.x, t = threadIdx.x;
    int s = 0;
    for (int blk = t; blk < nb; blk += 256) s += bh[(size_t)blk * 1024 + b];
    red[t] = s;
    __syncthreads();
    for (int off = 128; off; off >>= 1) {
        if (t < off) red[t] += red[t + off];
        __syncthreads();
    }
    if (t == 0) tot[b] = red[0];
}

__global__ __launch_bounds__(1024) void hscan_k(const int* __restrict__ hist,
                                                int* __restrict__ bcur) {
    __shared__ int s[1024];
    int t = threadIdx.x;
    s[t] = hist[t];
    __syncthreads();
    for (int off = 1; off < 1024; off <<= 1) {
        int val = (t >= off) ? s[t - off] : 0;
        __syncthreads();
        s[t] += val;
        __syncthreads();
    }
    bcur[t] = (t == 0) ? 0 : s[t - 1];
}

__global__ __launch_bounds__(256) void bbase_k(int* __restrict__ bh,
                                               const int* __restrict__ bstart, int nb) {
    __shared__ int s[256];
    int b = blockIdx.x, t = threadIdx.x;
    int v = (t < nb) ? bh[(size_t)t * 1024 + b] : 0;
    s[t] = v;
    __syncthreads();
    for (int off = 1; off < 256; off <<= 1) {
        int x = (t >= off) ? s[t - off] : 0;
        __syncthreads();
        s[t] += x;
        __syncthreads();
    }
    int excl = (t == 0) ? 0 : s[t - 1];
    if (t < nb) bh[(size_t)t * 1024 + b] = bstart[b] + excl;
}

__global__ __launch_bounds__(256) void pscatter_k(const int* __restrict__ deg,
                                                  const int* __restrict__ bh,
                                                  int* __restrict__ perm,
                                                  int* __restrict__ inv_perm, int n) {
    __shared__ int lh[1024];
    int t = threadIdx.x;
    for (int b = t; b < 1024; b += 256) lh[b] = 0;
    __syncthreads();
    int i = blockIdx.x * 256 + t;
    int b = 0, r = 0;
    if (i < n) {
        b = min(deg[i], 1023);
        r = atomicAdd(&lh[b], 1);
    }
    __syncthreads();
    if (i < n) {
        int pos = bh[(size_t)blockIdx.x * 1024 + b] + r;
        perm[pos] = i;
        inv_perm[i] = pos;
    }
}

// slot-space degree + dinv
__global__ __launch_bounds__(256) void degs_k(const int* __restrict__ deg,
                                              const int* __restrict__ perm,
                                              int* __restrict__ deg_s,
                                              float* __restrict__ dinv_s, int n) {
    int i = blockIdx.x * 256 + threadIdx.x;
    if (i < n) {
        int d = deg[perm[i]];
        deg_s[i] = d;
        dinv_s[i] = rsqrtf((float)d);
    }
}

// ---------------------------------------------------------------------------
// Device-wide exclusive scan of PADDED in-edge counts -> rp[0..n].
// P_i = ceil((deg_s[i]-1)/8)*8: every CSR row is a multiple of 8 so the
// aggregate's gather loop is pure 8-deep unrolled (no serial tail; r19's
// tail was ~e%8 ~ 3.5 edges at 1-outstanding-load latency per node).
// ---------------------------------------------------------------------------
__device__ __forceinline__ int padded8(int d) { return ((d - 1) + 7) & ~7; }

__global__ __launch_bounds__(256) void ppart_k(const int* __restrict__ deg,
                                               int* __restrict__ part, int n) {
    __shared__ int red[256];
    int t = threadIdx.x;
    int i = blockIdx.x * 256 + t;
    red[t] = (i < n) ? padded8(deg[i]) : 0;
    __syncthreads();
    for (int off = 128; off; off >>= 1) {
        if (t < off) red[t] += red[t + off];
        __syncthreads();
    }
    if (t == 0) part[blockIdx.x] = red[0];
}

__global__ __launch_bounds__(256) void pscan1_k(int* __restrict__ part, int nb) {
    __shared__ int s[256];
    int t = threadIdx.x;
    s[t] = (t < nb) ? part[t] : 0;
    __syncthreads();
    for (int off = 1; off < 256; off <<= 1) {
        int v = (t >= off) ? s[t - off] : 0;
        __syncthreads();
        s[t] += v;
        __syncthreads();
    }
    if (t < nb) part[t] = (t == 0) ? 0 : s[t - 1];
}

__global__ __launch_bounds__(256) void pwrite_k(const int* __restrict__ deg,
                                                const int* __restrict__ part,
                                                int* __restrict__ rp, int n) {
    __shared__ int s[256];
    int t = threadIdx.x;
    int i = blockIdx.x * 256 + t;
    int val = (i < n) ? padded8(deg[i]) : 0;
    s[t] = val;
    __syncthreads();
    for (int off = 1; off < 256; off <<= 1) {
        int v = (t >= off) ? s[t - off] : 0;
        __syncthreads();
        s[t] += v;
        __syncthreads();
    }
    int incl = s[t];
    if (i < n) rp[i] = part[blockIdx.x] + incl - val;
    if (i == n - 1) rp[n] = part[blockIdx.x] + incl;
}

// CSR scatter, ATOMIC-FREE: pos = rp[slot(r)] + rank[i]-1.
__global__ __launch_bounds__(256) void scatter_k(const void* __restrict__ edges,
                                                 const int* __restrict__ flag,
                                                 const int* __restrict__ inv_perm,
                                                 const int* __restrict__ rp,
                                                 const int* __restrict__ rank,
                                                 unsigned short* __restrict__ col_s, int e) {
    int i = blockIdx.x * 256 + threadIdx.x;
    if (i < e) {
        int is32 = *flag;
        int r = inv_perm[edge_at(edges, is32, i)];
        int c = inv_perm[edge_at(edges, is32, (long long)NE + i)];
        int pos = rp[r] + rank[i] - 1;
        col_s[pos] = (unsigned short)c;
    }
}

// Pad fill: positions rp[i]+e .. rp[i+1]-1 get the slot's OWN index. The
// aggregate compensates via acc = (1 - padcount)*G[v] (exact up to fp32
// reassociation noise; pads are L1-hot self-row reads).
__global__ __launch_bounds__(256) void padfill_k(const int* __restrict__ deg_s,
                                                 const int* __restrict__ rp,
                                                 unsigned short* __restrict__ col_s, int n) {
    int i = blockIdx.x * 256 + threadIdx.x;
    if (i < n) {
        int e = deg_s[i] - 1;
        int beg = rp[i] + e, end = rp[i + 1];
        for (int j = beg; j < end; ++j) col_s[j] = (unsigned short)i;
    }
}

// ---------------------------------------------------------------------------
// Hadamard: fully sequential stream (r18). X0 row-major [node][256] fp16.
// ---------------------------------------------------------------------------
__global__ __launch_bounds__(256) void hadamard_k(const float4* __restrict__ a,
                                                  const float4* __restrict__ b,
                                                  _Float16* __restrict__ X0, int n8) {
    int i = blockIdx.x * 256 + threadIdx.x;   // each handles 8 fp32
    if (i >= n8) return;
    float4 x0 = a[2 * i], x1 = a[2 * i + 1];
    float4 y0 = b[2 * i], y1 = b[2 * i + 1];
    f16x8 h;
    h[0] = (_Float16)(x0.x * y0.x);
    h[1] = (_Float16)(x0.y * y0.y);
    h[2] = (_Float16)(x0.z * y0.z);
    h[3] = (_Float16)(x0.w * y0.w);
    h[4] = (_Float16)(x1.x * y1.x);
    h[5] = (_Float16)(x1.y * y1.y);
    h[6] = (_Float16)(x1.z * y1.z);
    h[7] = (_Float16)(x1.w * y1.w);
    *(f16x8*)&X0[(size_t)i * 8] = h;
}

// ---------------------------------------------------------------------------
// W convert: W[K=256][Nout] fp32 -> B3 [Nout][512] fp16, layout [Wh | Wl]
// ---------------------------------------------------------------------------
__global__ __launch_bounds__(256) void wconv_k(const float* __restrict__ W,
                                               _Float16* __restrict__ B3, int Nout) {
    int n = blockIdx.x;            // 0..Nout-1
    int k = threadIdx.x;           // 0..255
    float v = W[(size_t)k * Nout + n];
    _Float16 h = (_Float16)v;
    B3[(size_t)n * 512 + k]       = h;
    B3[(size_t)n * 512 + 256 + k] = (_Float16)(v - (float)h);
}

// ---------------------------------------------------------------------------
// fp16 MFMA GEMM over virtual K=512, double-buffered LDS, XOR chunk-swizzle.
// PERMA=0: A slot-major panels; PERMA=1: row-major X0 via per-lane perm src.
// Epilogue writes G = dinv_s[row] * (A@W).
// ---------------------------------------------------------------------------
__device__ __forceinline__ void gload_lds16(const void* g, void* l) {
    __builtin_amdgcn_global_load_lds(
        (const __attribute__((address_space(1))) void*)g,
        (__attribute__((address_space(3))) void*)l, 16, 0, 0);
}

template <int NBX, int SW, int PERMA>
__global__ __launch_bounds__(256) void gemm_f16_k(const _Float16* __restrict__ Ah,
                                                  const _Float16* __restrict__ B3,
                                                  const float* __restrict__ dinv_s,
                                                  const int* __restrict__ perm,
                                                  _Float16* __restrict__ C,
                                                  int M, int Nout) {
    __shared__ alignas(16) _Float16 sA[2][128 * 32];
    __shared__ alignas(16) _Float16 sB[2][128 * 32];
    constexpr int LG = (SW == 32) ? 5 : 4;
    constexpr int NST = 16;           // K = 512 / 32
    int mblk = (M + 127) >> 7;

    int pair, xb;
    if (NBX == 2) {
        int b = blockIdx.x;
        pair = (b >> 4) * 8 + (b & 7);     // row-panel id; pinned to XCD (b&7)
        xb   = (b >> 3) & 1;
        if (pair >= mblk) return;
    } else {
        pair = blockIdx.x;
        xb = 0;
    }

    int tid = threadIdx.x;
    int row0 = pair * 128, col0 = xb * 128;
    int wid = tid >> 6, lane = tid & 63;
    int wm = wid >> 1, wn = wid & 1;
    int fr = lane & 15;
    int kbc = lane >> 4;            // k chunk index 0..3 (8 fp16 each)

    int sr = lane >> 2;             // staging row within 16-row chunk
    int ke = (((lane & 3) ^ ((sr >> 1) & 3)) * 8);   // pre-swizzled source chunk

    int arow_c[2], vsrc[2];
    #pragma unroll
    for (int c = 0; c < 2; ++c) {
        arow_c[c] = row0 + (wid * 2 + c) * 16 + sr;
        if (PERMA)
            vsrc[c] = (arow_c[c] < M) ? perm[arow_c[c]] : 0;
    }

    f32x4 acc[4][4] = {};

    auto STAGE = [&](int bsel, int s) {
        int p = s & 7;                    // A k-panel index
        #pragma unroll
        for (int c = 0; c < 2; ++c) {
            int ch = wid * 2 + c;         // 0..7
            if (arow_c[c] < M) {
                if (PERMA)
                    gload_lds16(&Ah[(size_t)vsrc[c] * 256 + p * 32 + ke], &sA[bsel][ch * 512]);
                else
                    gload_lds16(&Ah[((size_t)p * M + arow_c[c]) * 32 + ke], &sA[bsel][ch * 512]);
            }
            int r = ch * 16 + sr;
            gload_lds16(&B3[(size_t)(col0 + r) * 512 + s * 32 + ke], &sB[bsel][ch * 512]);
        }
    };

    STAGE(0, 0);
    __syncthreads();
    int cur = 0;

    for (int s = 0; s < NST; ++s) {
        if (s + 1 < NST) STAGE(cur ^ 1, s + 1);

        f16x8 af[4];
        #pragma unroll
        for (int f = 0; f < 4; ++f) {
            int rr = wm * 64 + f * 16 + fr;
            af[f] = *(const f16x8*)&sA[cur][rr * 32 + ((kbc ^ ((rr >> 1) & 3)) * 8)];
        }
        #pragma unroll
        for (int g = 0; g < 4; ++g) {
            int cc = wn * 64 + g * 16 + fr;
            f16x8 bf_ = *(const f16x8*)&sB[cur][cc * 32 + ((kbc ^ ((cc >> 1) & 3)) * 8)];
            #pragma unroll
            for (int f = 0; f < 4; ++f)
                acc[f][g] = __builtin_amdgcn_mfma_f32_16x16x32_f16(af[f], bf_, acc[f][g], 0, 0, 0);
        }

        __syncthreads();
        cur ^= 1;
    }

    int rsub = (lane >> 4) * 4;
    float dsc[4][4];
    #pragma unroll
    for (int f = 0; f < 4; ++f)
        #pragma unroll
        for (int r = 0; r < 4; ++r) {
            int row = row0 + wm * 64 + f * 16 + rsub + r;
            dsc[f][r] = (row < M) ? dinv_s[row] : 0.0f;
        }
    #pragma unroll
    for (int f = 0; f < 4; ++f) {
        #pragma unroll
        for (int g = 0; g < 4; ++g) {
            int col = col0 + wn * 64 + g * 16 + fr;
            #pragma unroll
            for (int r = 0; r < 4; ++r) {
                int row = row0 + wm * 64 + f * 16 + rsub + r;
                if (row < M)
                    C[((size_t)(col >> LG) * M + row) * SW + (col & (SW - 1))] =
                        (_Float16)(acc[f][g][r] * dsc[f][r]);
            }
        }
    }
}

// ---------------------------------------------------------------------------
// XCD-sliced aggregation v9: padded CSR -> pure 8-deep unrolled gather loop,
// no serial tail. Pads point at the destination slot itself; compensated by
// acc = (1 - padcount) * G[v]. slot-space, uint16 cs.
// MODE 0: relu, slot-major fp16 out. MODE 1: fp32 scatter to orig rows.
// ---------------------------------------------------------------------------
template <int D, int MODE>
__global__ __launch_bounds__(256) void aggregate_slice_k(const _Float16* __restrict__ G,
                                                         const float* __restrict__ bias,
                                                         const float* __restrict__ dinv_s,
                                                         const int* __restrict__ deg_s,
                                                         const int* __restrict__ rp,
                                                         const unsigned short* __restrict__ cs,
                                                         const int* __restrict__ perm,
                                                         _Float16* __restrict__ Yh,
                                                         float* __restrict__ Yf, int n) {
    constexpr int SLICE = (D == 256) ? 32 : 16;   // panel width
    constexpr int LPN = SLICE / 8;                // lanes per node (f16x8 each)
    constexpr int NPB = 256 / LPN;                // nodes per block

    int bid = blockIdx.x;
    int s = bid & 7;
    int slot = (bid >> 3) * NPB + threadIdx.x / LPN;
    if (slot >= n) return;
    int sub = threadIdx.x % LPN;
    int co = sub * 8;                             // within-panel col offset
    int col = s * SLICE + co;                     // global col (bias / out)

    const _Float16* Gs = G + (size_t)s * n * SLICE;   // this slice's panel

    int beg = rp[slot], end = rp[slot + 1];
    int pads = (end - beg) - (deg_s[slot] - 1);
    float m = 1.0f - (float)pads;

    float acc[8];
    {
        f16x8 t0 = *(const f16x8*)&Gs[(size_t)slot * SLICE + co];
        #pragma unroll
        for (int i = 0; i < 8; ++i) acc[i] = m * (float)t0[i];
    }

    for (int j = beg; j < end; j += 8) {          // padded: always full 8
        int cc[8];
        #pragma unroll
        for (int u = 0; u < 8; ++u) cc[u] = cs[j + u];
        f16x8 hv[8];
        #pragma unroll
        for (int u = 0; u < 8; ++u)
            hv[u] = *(const f16x8*)&Gs[(size_t)cc[u] * SLICE + co];
        #pragma unroll
        for (int u = 0; u < 8; ++u)
            #pragma unroll
            for (int i = 0; i < 8; ++i)
                acc[i] += (float)hv[u][i];
    }

    float dv = dinv_s[slot];
    float4 b0 = *(const float4*)&bias[col];
    float4 b1 = *(const float4*)&bias[col + 4];
    float bb[8] = { b0.x, b0.y, b0.z, b0.w, b1.x, b1.y, b1.z, b1.w };

    if constexpr (MODE == 0) {
        f16x8 hh;
        #pragma unroll
        for (int i = 0; i < 8; ++i)
            hh[i] = (_Float16)fmaxf(dv * acc[i] + bb[i], 0.0f);
        size_t off = ((size_t)s * n + slot) * SLICE + co;   // slot-major out
        *(f16x8*)&Yh[off] = hh;
    } else {
        int v = perm[slot];                                 // orig node id
        float o[8];
        #pragma unroll
        for (int i = 0; i < 8; ++i) o[i] = dv * acc[i] + bb[i];
        *(float4*)&Yf[(size_t)v * D + col]     = make_float4(o[0], o[1], o[2], o[3]);
        *(float4*)&Yf[(size_t)v * D + col + 4] = make_float4(o[4], o[5], o[6], o[7]);
    }
}

// ---------------------------------------------------------------------------
extern "C" void kernel_launch(void* const* d_in, const int* in_sizes, int n_in,
                              void* d_out, int out_size, void* d_ws, size_t ws_size,
                              hipStream_t stream) {
    const float* qe  = (const float*)d_in[0];
    const float* obj = (const float*)d_in[1];
    const void*  edges = d_in[2];
    const float* W1 = (const float*)d_in[3];
    const float* b1 = (const float*)d_in[4];
    const float* W2 = (const float*)d_in[5];
    const float* b2 = (const float*)d_in[6];
    const float* W3 = (const float*)d_in[7];
    const float* b3 = (const float*)d_in[8];
    float* out = (float*)d_out;

    char* p = (char*)d_ws;
    _Float16* Xh   = (_Float16*)p; p += (size_t)NN * 256 * 2;   // 25.6 MB
    _Float16* H    = (_Float16*)p; p += (size_t)NN * 256 * 2;   // 25.6 MB
    _Float16* B3   = (_Float16*)p; p += (size_t)256 * 512 * 2;  // 0.26 MB
    int*   dacc    = (int*)p;   p += (size_t)NN * 32 * 4;       // 6.4 MB (1/line)
    int*   rank    = (int*)p;   p += (size_t)NE * 4;            // 3.2 MB
    int*   deg     = (int*)p;   p += (size_t)NN * 4;
    int*   deg_s   = (int*)p;   p += (size_t)NN * 4;
    float* dinv_s  = (float*)p; p += (size_t)NN * 4;
    int*   rp      = (int*)p;   p += (size_t)(NN + 1) * 4;
    unsigned short* col_s = (unsigned short*)p; p += (size_t)(NE + NN * 8) * 2;  // padded
    int*   bh      = (int*)p;   p += (size_t)NBLK * 1024 * 4;   // 0.8 MB
    int*   tot     = (int*)p;   p += 1024 * 4;
    int*   bstart  = (int*)p;   p += 1024 * 4;
    int*   part    = (int*)p;   p += NBLK * 4;
    int*   perm    = (int*)p;   p += (size_t)NN * 4;
    int*   inv_perm= (int*)p;   p += (size_t)NN * 4;
    int*   flag    = (int*)p;   p += 4;

    zero_flag_k<<<1, 64, 0, stream>>>(flag);
    detect_k<<<4, 256, 0, stream>>>((const int*)edges, flag);
    init_k<<<(NN + 255) / 256, 256, 0, stream>>>(dacc, NN);
    count_k<<<(NE + 255) / 256, 256, 0, stream>>>(edges, flag, dacc, rank, NE);
    dcompact_k<<<(NN + 255) / 256, 256, 0, stream>>>(dacc, deg, NN);
    // degree-sorted renumbering
    bh_k<<<NBLK, 256, 0, stream>>>(deg, bh, NN);
    btot_k<<<1024, 256, 0, stream>>>(bh, tot, NBLK);
    hscan_k<<<1, 1024, 0, stream>>>(tot, bstart);
    bbase_k<<<1024, 256, 0, stream>>>(bh, bstart, NBLK);
    pscatter_k<<<NBLK, 256, 0, stream>>>(deg, bh, perm, inv_perm, NN);
    degs_k<<<NBLK, 256, 0, stream>>>(deg, perm, deg_s, dinv_s, NN);
    // rp over PADDED slot-space counts
    ppart_k<<<NBLK, 256, 0, stream>>>(deg_s, part, NN);
    pscan1_k<<<1, 256, 0, stream>>>(part, NBLK);
    pwrite_k<<<NBLK, 256, 0, stream>>>(deg_s, part, rp, NN);
    // translated CSR (uint16 columns), atomic-free + pad fill
    scatter_k<<<(NE + 255) / 256, 256, 0, stream>>>(edges, flag, inv_perm, rp, rank,
                                                    col_s, NE);
    padfill_k<<<NBLK, 256, 0, stream>>>(deg_s, rp, col_s, NN);
    // X0 = qe*obj, sequential stream, row-major original order
    hadamard_k<<<(NN * 32 + 255) / 256, 256, 0, stream>>>(
        (const float4*)qe, (const float4*)obj, Xh, NN * 32);

    int mblk = (NN + 127) / 128;                 // 391
    int gemmBigGrid = ((mblk + 7) / 8) * 16;     // 800 (pair-swizzled, 2 col blocks)
    int agg256Grid = ((NN + 63) / 64) * 8;       // 6256
    int agg128Grid = ((NN + 127) / 128) * 8;     // 3128

    // Layer 1 (perm-indirect A staging from row-major X0)
    wconv_k<<<256, 256, 0, stream>>>(W1, B3, 256);
    gemm_f16_k<2, 32, 1><<<gemmBigGrid, 256, 0, stream>>>(Xh, B3, dinv_s, perm, H, NN, 256);
    aggregate_slice_k<256, 0><<<agg256Grid, 256, 0, stream>>>(H, b1, dinv_s, deg_s, rp, col_s,
                                                              perm, Xh, nullptr, NN);
    // Layer 2 (linear panel staging)
    wconv_k<<<256, 256, 0, stream>>>(W2, B3, 256);
    gemm_f16_k<2, 32, 0><<<gemmBigGrid, 256, 0, stream>>>(Xh, B3, dinv_s, perm, H, NN, 256);
    aggregate_slice_k<256, 0><<<agg256Grid, 256, 0, stream>>>(H, b2, dinv_s, deg_s, rp, col_s,
                                                              perm, Xh, nullptr, NN);
    // Layer 3
    wconv_k<<<128, 256, 0, stream>>>(W3, B3, 128);
    gemm_f16_k<1, 16, 0><<<mblk, 256, 0, stream>>>(Xh, B3, dinv_s, perm, H, NN, 128);
    aggregate_slice_k<128, 1><<<agg128Grid, 256, 0, stream>>>(H, b3, dinv_s, deg_s, rp, col_s,
                                                              perm, nullptr, out, NN);
}

// Round 21
// 303.030 us; speedup vs baseline: 1.0986x; 1.0174x over previous
//
#include <hip/hip_runtime.h>
#include <cstdint>
#include <cstddef>

#define NN 50000
#define NE 800000
#define NBLK ((NN + 255) / 256)   // 196 node-chunks

typedef _Float16 f16x8 __attribute__((ext_vector_type(8)));
typedef _Float16 f16x4 __attribute__((ext_vector_type(4)));
typedef unsigned short u16x8 __attribute__((ext_vector_type(8)));
typedef float f32x4 __attribute__((ext_vector_type(4)));

// ---------------------------------------------------------------------------
// Edge-index dtype robustness (int64 vs int32 canonicalization)
// ---------------------------------------------------------------------------
__device__ __forceinline__ int edge_at(const void* e, int is32, long long i) {
    return is32 ? ((const int*)e)[i] : (int)((const long long*)e)[i];
}

__global__ __launch_bounds__(64) void zero_flag_k(int* flag) {
    if (threadIdx.x == 0) *flag = 0;
}

__global__ __launch_bounds__(256) void detect_k(const int* __restrict__ w, int* __restrict__ flag) {
    int i = blockIdx.x * 256 + threadIdx.x;   // 0..1023
    if (i < 1024 && w[2 * i + 1] != 0) atomicOr(flag, 1);
}

// ---------------------------------------------------------------------------
// Degree count with RANK CAPTURE (r19). dacc strided 1-per-128B-line (r16).
// ---------------------------------------------------------------------------
__global__ __launch_bounds__(256) void init_k(int* __restrict__ dacc, int n) {
    int i = blockIdx.x * 256 + threadIdx.x;
    if (i < n) dacc[(size_t)i * 32] = 1;
}

__global__ __launch_bounds__(256) void count_k(const void* __restrict__ edges,
                                               const int* __restrict__ flag,
                                               int* __restrict__ dacc,
                                               int* __restrict__ rank, int e) {
    int i = blockIdx.x * 256 + threadIdx.x;
    if (i < e) {
        int is32 = *flag;
        rank[i] = atomicAdd(&dacc[(size_t)edge_at(edges, is32, i) * 32], 1);
    }
}

// ---------------------------------------------------------------------------
// Degree-sorted renumbering, contention-free counting sort.
// bh_k: fused dacc compaction (writes deg) + per-block LDS histogram.
// ---------------------------------------------------------------------------
__global__ __launch_bounds__(256) void bh_k(const int* __restrict__ dacc,
                                            int* __restrict__ deg,
                                            int* __restrict__ bh, int n) {
    __shared__ int lh[1024];
    int t = threadIdx.x;
    for (int b = t; b < 1024; b += 256) lh[b] = 0;
    __syncthreads();
    int i = blockIdx.x * 256 + t;
    if (i < n) {
        int d = dacc[(size_t)i * 32];
        deg[i] = d;
        atomicAdd(&lh[min(d, 1023)], 1);
    }
    __syncthreads();
    for (int b = t; b < 1024; b += 256) bh[(size_t)blockIdx.x * 1024 + b] = lh[b];
}

__global__ __launch_bounds__(256) void btot_k(const int* __restrict__ bh,
                                              int* __restrict__ tot, int nb) {
    __shared__ int red[256];
    int b = blockIdx.x, t = threadIdx.x;
    int s = 0;
    for (int blk = t; blk < nb; blk += 256) s += bh[(size_t)blk * 1024 + b];
    red[t] = s;
    __syncthreads();
    for (int off = 128; off; off >>= 1) {
        if (t < off) red[t] += red[t + off];
        __syncthreads();
    }
    if (t == 0) tot[b] = red[0];
}

__global__ __launch_bounds__(1024) void hscan_k(const int* __restrict__ hist,
                                                int* __restrict__ bcur) {
    __shared__ int s[1024];
    int t = threadIdx.x;
    s[t] = hist[t];
    __syncthreads();
    for (int off = 1; off < 1024; off <<= 1) {
        int val = (t >= off) ? s[t - off] : 0;
        __syncthreads();
        s[t] += val;
        __syncthreads();
    }
    bcur[t] = (t == 0) ? 0 : s[t - 1];
}

__global__ __launch_bounds__(256) void bbase_k(int* __restrict__ bh,
                                               const int* __restrict__ bstart, int nb) {
    __shared__ int s[256];
    int b = blockIdx.x, t = threadIdx.x;
    int v = (t < nb) ? bh[(size_t)t * 1024 + b] : 0;
    s[t] = v;
    __syncthreads();
    for (int off = 1; off < 256; off <<= 1) {
        int x = (t >= off) ? s[t - off] : 0;
        __syncthreads();
        s[t] += x;
        __syncthreads();
    }
    int excl = (t == 0) ? 0 : s[t - 1];
    if (t < nb) bh[(size_t)t * 1024 + b] = bstart[b] + excl;
}

// pscatter + fused slot-space deg/dinv production.
__global__ __launch_bounds__(256) void pscatter_k(const int* __restrict__ deg,
                                                  const int* __restrict__ bh,
                                                  int* __restrict__ perm,
                                                  int* __restrict__ inv_perm,
                                                  int* __restrict__ deg_s,
                                                  float* __restrict__ dinv_s, int n) {
    __shared__ int lh[1024];
    int t = threadIdx.x;
    for (int b = t; b < 1024; b += 256) lh[b] = 0;
    __syncthreads();
    int i = blockIdx.x * 256 + t;
    int b = 0, r = 0, d = 0;
    if (i < n) {
        d = deg[i];
        b = min(d, 1023);
        r = atomicAdd(&lh[b], 1);
    }
    __syncthreads();
    if (i < n) {
        int pos = bh[(size_t)blockIdx.x * 1024 + b] + r;
        perm[pos] = i;
        inv_perm[i] = pos;
        deg_s[pos] = d;
        dinv_s[pos] = rsqrtf((float)d);
    }
}

// ---------------------------------------------------------------------------
// Device-wide exclusive scan of PADDED in-edge counts -> rp[0..n] (r20).
// pwrite fuses the pad fill (pads = slot's own index; positions past the
// real edges, which scatter_k never touches).
// ---------------------------------------------------------------------------
__device__ __forceinline__ int padded8(int d) { return ((d - 1) + 7) & ~7; }

__global__ __launch_bounds__(256) void ppart_k(const int* __restrict__ deg,
                                               int* __restrict__ part, int n) {
    __shared__ int red[256];
    int t = threadIdx.x;
    int i = blockIdx.x * 256 + t;
    red[t] = (i < n) ? padded8(deg[i]) : 0;
    __syncthreads();
    for (int off = 128; off; off >>= 1) {
        if (t < off) red[t] += red[t + off];
        __syncthreads();
    }
    if (t == 0) part[blockIdx.x] = red[0];
}

__global__ __launch_bounds__(256) void pscan1_k(int* __restrict__ part, int nb) {
    __shared__ int s[256];
    int t = threadIdx.x;
    s[t] = (t < nb) ? part[t] : 0;
    __syncthreads();
    for (int off = 1; off < 256; off <<= 1) {
        int v = (t >= off) ? s[t - off] : 0;
        __syncthreads();
        s[t] += v;
        __syncthreads();
    }
    if (t < nb) part[t] = (t == 0) ? 0 : s[t - 1];
}

__global__ __launch_bounds__(256) void pwrite_k(const int* __restrict__ deg_s,
                                                const int* __restrict__ part,
                                                int* __restrict__ rp,
                                                unsigned short* __restrict__ col_s, int n) {
    __shared__ int s[256];
    int t = threadIdx.x;
    int i = blockIdx.x * 256 + t;
    int val = (i < n) ? padded8(deg_s[i]) : 0;
    s[t] = val;
    __syncthreads();
    for (int off = 1; off < 256; off <<= 1) {
        int v = (t >= off) ? s[t - off] : 0;
        __syncthreads();
        s[t] += v;
        __syncthreads();
    }
    int incl = s[t];
    if (i < n) {
        int rpi = part[blockIdx.x] + incl - val;
        rp[i] = rpi;
        int e = deg_s[i] - 1;
        for (int j = rpi + e; j < rpi + val; ++j) col_s[j] = (unsigned short)i;  // pads
    }
    if (i == n - 1) rp[n] = part[blockIdx.x] + incl;
}

// CSR scatter, ATOMIC-FREE: pos = rp[slot(r)] + rank[i]-1.
__global__ __launch_bounds__(256) void scatter_k(const void* __restrict__ edges,
                                                 const int* __restrict__ flag,
                                                 const int* __restrict__ inv_perm,
                                                 const int* __restrict__ rp,
                                                 const int* __restrict__ rank,
                                                 unsigned short* __restrict__ col_s, int e) {
    int i = blockIdx.x * 256 + threadIdx.x;
    if (i < e) {
        int is32 = *flag;
        int r = inv_perm[edge_at(edges, is32, i)];
        int c = inv_perm[edge_at(edges, is32, (long long)NE + i)];
        int pos = rp[r] + rank[i] - 1;
        col_s[pos] = (unsigned short)c;
    }
}

// ---------------------------------------------------------------------------
// Hadamard: fully sequential stream (r18). X0 row-major [node][256] fp16.
// ---------------------------------------------------------------------------
__global__ __launch_bounds__(256) void hadamard_k(const float4* __restrict__ a,
                                                  const float4* __restrict__ b,
                                                  _Float16* __restrict__ X0, int n8) {
    int i = blockIdx.x * 256 + threadIdx.x;   // each handles 8 fp32
    if (i >= n8) return;
    float4 x0 = a[2 * i], x1 = a[2 * i + 1];
    float4 y0 = b[2 * i], y1 = b[2 * i + 1];
    f16x8 h;
    h[0] = (_Float16)(x0.x * y0.x);
    h[1] = (_Float16)(x0.y * y0.y);
    h[2] = (_Float16)(x0.z * y0.z);
    h[3] = (_Float16)(x0.w * y0.w);
    h[4] = (_Float16)(x1.x * y1.x);
    h[5] = (_Float16)(x1.y * y1.y);
    h[6] = (_Float16)(x1.z * y1.z);
    h[7] = (_Float16)(x1.w * y1.w);
    *(f16x8*)&X0[(size_t)i * 8] = h;
}

// ---------------------------------------------------------------------------
// W convert: W[K=256][Nout] fp32 -> B3 [Nout][512] fp16, layout [Wh | Wl]
// ---------------------------------------------------------------------------
__global__ __launch_bounds__(256) void wconv_k(const float* __restrict__ W,
                                               _Float16* __restrict__ B3, int Nout) {
    int n = blockIdx.x;            // 0..Nout-1
    int k = threadIdx.x;           // 0..255
    float v = W[(size_t)k * Nout + n];
    _Float16 h = (_Float16)v;
    B3[(size_t)n * 512 + k]       = h;
    B3[(size_t)n * 512 + 256 + k] = (_Float16)(v - (float)h);
}

// ---------------------------------------------------------------------------
// fp16 MFMA GEMM over virtual K=512, double-buffered LDS, XOR chunk-swizzle.
// PERMA=0: A slot-major panels; PERMA=1: row-major X0 via per-lane perm src.
// Epilogue writes G = dinv_s[row] * (A@W).
// ---------------------------------------------------------------------------
__device__ __forceinline__ void gload_lds16(const void* g, void* l) {
    __builtin_amdgcn_global_load_lds(
        (const __attribute__((address_space(1))) void*)g,
        (__attribute__((address_space(3))) void*)l, 16, 0, 0);
}

template <int NBX, int SW, int PERMA>
__global__ __launch_bounds__(256) void gemm_f16_k(const _Float16* __restrict__ Ah,
                                                  const _Float16* __restrict__ B3,
                                                  const float* __restrict__ dinv_s,
                                                  const int* __restrict__ perm,
                                                  _Float16* __restrict__ C,
                                                  int M, int Nout) {
    __shared__ alignas(16) _Float16 sA[2][128 * 32];
    __shared__ alignas(16) _Float16 sB[2][128 * 32];
    constexpr int LG = (SW == 32) ? 5 : 4;
    constexpr int NST = 16;           // K = 512 / 32
    int mblk = (M + 127) >> 7;

    int pair, xb;
    if (NBX == 2) {
        int b = blockIdx.x;
        pair = (b >> 4) * 8 + (b & 7);     // row-panel id; pinned to XCD (b&7)
        xb   = (b >> 3) & 1;
        if (pair >= mblk) return;
    } else {
        pair = blockIdx.x;
        xb = 0;
    }

    int tid = threadIdx.x;
    int row0 = pair * 128, col0 = xb * 128;
    int wid = tid >> 6, lane = tid & 63;
    int wm = wid >> 1, wn = wid & 1;
    int fr = lane & 15;
    int kbc = lane >> 4;            // k chunk index 0..3 (8 fp16 each)

    int sr = lane >> 2;             // staging row within 16-row chunk
    int ke = (((lane & 3) ^ ((sr >> 1) & 3)) * 8);   // pre-swizzled source chunk

    int arow_c[2], vsrc[2];
    #pragma unroll
    for (int c = 0; c < 2; ++c) {
        arow_c[c] = row0 + (wid * 2 + c) * 16 + sr;
        if (PERMA)
            vsrc[c] = (arow_c[c] < M) ? perm[arow_c[c]] : 0;
    }

    f32x4 acc[4][4] = {};

    auto STAGE = [&](int bsel, int s) {
        int p = s & 7;                    // A k-panel index
        #pragma unroll
        for (int c = 0; c < 2; ++c) {
            int ch = wid * 2 + c;         // 0..7
            if (arow_c[c] < M) {
                if (PERMA)
                    gload_lds16(&Ah[(size_t)vsrc[c] * 256 + p * 32 + ke], &sA[bsel][ch * 512]);
                else
                    gload_lds16(&Ah[((size_t)p * M + arow_c[c]) * 32 + ke], &sA[bsel][ch * 512]);
            }
            int r = ch * 16 + sr;
            gload_lds16(&B3[(size_t)(col0 + r) * 512 + s * 32 + ke], &sB[bsel][ch * 512]);
        }
    };

    STAGE(0, 0);
    __syncthreads();
    int cur = 0;

    for (int s = 0; s < NST; ++s) {
        if (s + 1 < NST) STAGE(cur ^ 1, s + 1);

        f16x8 af[4];
        #pragma unroll
        for (int f = 0; f < 4; ++f) {
            int rr = wm * 64 + f * 16 + fr;
            af[f] = *(const f16x8*)&sA[cur][rr * 32 + ((kbc ^ ((rr >> 1) & 3)) * 8)];
        }
        #pragma unroll
        for (int g = 0; g < 4; ++g) {
            int cc = wn * 64 + g * 16 + fr;
            f16x8 bf_ = *(const f16x8*)&sB[cur][cc * 32 + ((kbc ^ ((cc >> 1) & 3)) * 8)];
            #pragma unroll
            for (int f = 0; f < 4; ++f)
                acc[f][g] = __builtin_amdgcn_mfma_f32_16x16x32_f16(af[f], bf_, acc[f][g], 0, 0, 0);
        }

        __syncthreads();
        cur ^= 1;
    }

    int rsub = (lane >> 4) * 4;
    float dsc[4][4];
    #pragma unroll
    for (int f = 0; f < 4; ++f)
        #pragma unroll
        for (int r = 0; r < 4; ++r) {
            int row = row0 + wm * 64 + f * 16 + rsub + r;
            dsc[f][r] = (row < M) ? dinv_s[row] : 0.0f;
        }
    #pragma unroll
    for (int f = 0; f < 4; ++f) {
        #pragma unroll
        for (int g = 0; g < 4; ++g) {
            int col = col0 + wn * 64 + g * 16 + fr;
            #pragma unroll
            for (int r = 0; r < 4; ++r) {
                int row = row0 + wm * 64 + f * 16 + rsub + r;
                if (row < M)
                    C[((size_t)(col >> LG) * M + row) * SW + (col & (SW - 1))] =
                        (_Float16)(acc[f][g][r] * dsc[f][r]);
            }
        }
    }
}

// ---------------------------------------------------------------------------
// XCD-sliced aggregation v10: padded CSR, pure 8-deep unrolled gather,
// ONE u16x8 vector load per iteration for the 8 column ids (was 8 scalar
// loads x 4 redundant lanes; rp multiples of 8 -> cs[j] is 16B-aligned).
// Pads = destination slot, compensated by acc = (1-padcount)*G[v].
// ---------------------------------------------------------------------------
template <int D, int MODE>
__global__ __launch_bounds__(256) void aggregate_slice_k(const _Float16* __restrict__ G,
                                                         const float* __restrict__ bias,
                                                         const float* __restrict__ dinv_s,
                                                         const int* __restrict__ deg_s,
                                                         const int* __restrict__ rp,
                                                         const unsigned short* __restrict__ cs,
                                                         const int* __restrict__ perm,
                                                         _Float16* __restrict__ Yh,
                                                         float* __restrict__ Yf, int n) {
    constexpr int SLICE = (D == 256) ? 32 : 16;   // panel width
    constexpr int LPN = SLICE / 8;                // lanes per node (f16x8 each)
    constexpr int NPB = 256 / LPN;                // nodes per block

    int bid = blockIdx.x;
    int s = bid & 7;
    int slot = (bid >> 3) * NPB + threadIdx.x / LPN;
    if (slot >= n) return;
    int sub = threadIdx.x % LPN;
    int co = sub * 8;                             // within-panel col offset
    int col = s * SLICE + co;                     // global col (bias / out)

    const _Float16* Gs = G + (size_t)s * n * SLICE;   // this slice's panel

    int beg = rp[slot], end = rp[slot + 1];
    int pads = (end - beg) - (deg_s[slot] - 1);
    float m = 1.0f - (float)pads;

    float acc[8];
    {
        f16x8 t0 = *(const f16x8*)&Gs[(size_t)slot * SLICE + co];
        #pragma unroll
        for (int i = 0; i < 8; ++i) acc[i] = m * (float)t0[i];
    }

    for (int j = beg; j < end; j += 8) {          // padded: always full 8
        u16x8 cc8 = *(const u16x8*)&cs[j];        // one 16B load, broadcast
        f16x8 hv[8];
        #pragma unroll
        for (int u = 0; u < 8; ++u)
            hv[u] = *(const f16x8*)&Gs[(size_t)cc8[u] * SLICE + co];
        #pragma unroll
        for (int u = 0; u < 8; ++u)
            #pragma unroll
            for (int i = 0; i < 8; ++i)
                acc[i] += (float)hv[u][i];
    }

    float dv = dinv_s[slot];
    float4 b0 = *(const float4*)&bias[col];
    float4 b1 = *(const float4*)&bias[col + 4];
    float bb[8] = { b0.x, b0.y, b0.z, b0.w, b1.x, b1.y, b1.z, b1.w };

    if constexpr (MODE == 0) {
        f16x8 hh;
        #pragma unroll
        for (int i = 0; i < 8; ++i)
            hh[i] = (_Float16)fmaxf(dv * acc[i] + bb[i], 0.0f);
        size_t off = ((size_t)s * n + slot) * SLICE + co;   // slot-major out
        *(f16x8*)&Yh[off] = hh;
    } else {
        int v = perm[slot];                                 // orig node id
        float o[8];
        #pragma unroll
        for (int i = 0; i < 8; ++i) o[i] = dv * acc[i] + bb[i];
        *(float4*)&Yf[(size_t)v * D + col]     = make_float4(o[0], o[1], o[2], o[3]);
        *(float4*)&Yf[(size_t)v * D + col + 4] = make_float4(o[4], o[5], o[6], o[7]);
    }
}

// ---------------------------------------------------------------------------
extern "C" void kernel_launch(void* const* d_in, const int* in_sizes, int n_in,
                              void* d_out, int out_size, void* d_ws, size_t ws_size,
                              hipStream_t stream) {
    const float* qe  = (const float*)d_in[0];
    const float* obj = (const float*)d_in[1];
    const void*  edges = d_in[2];
    const float* W1 = (const float*)d_in[3];
    const float* b1 = (const float*)d_in[4];
    const float* W2 = (const float*)d_in[5];
    const float* b2 = (const float*)d_in[6];
    const float* W3 = (const float*)d_in[7];
    const float* b3 = (const float*)d_in[8];
    float* out = (float*)d_out;

    char* p = (char*)d_ws;
    _Float16* Xh   = (_Float16*)p; p += (size_t)NN * 256 * 2;   // 25.6 MB
    _Float16* H    = (_Float16*)p; p += (size_t)NN * 256 * 2;   // 25.6 MB
    _Float16* B3   = (_Float16*)p; p += (size_t)256 * 512 * 2;  // 0.26 MB
    int*   dacc    = (int*)p;   p += (size_t)NN * 32 * 4;       // 6.4 MB (1/line)
    int*   rank    = (int*)p;   p += (size_t)NE * 4;            // 3.2 MB
    int*   deg     = (int*)p;   p += (size_t)NN * 4;
    int*   deg_s   = (int*)p;   p += (size_t)NN * 4;
    float* dinv_s  = (float*)p; p += (size_t)NN * 4;
    int*   rp      = (int*)p;   p += (size_t)(NN + 4) * 4;      // padded: col_s 16B-aligned
    unsigned short* col_s = (unsigned short*)p; p += (size_t)(NE + NN * 8) * 2;  // padded CSR
    int*   bh      = (int*)p;   p += (size_t)NBLK * 1024 * 4;   // 0.8 MB
    int*   tot     = (int*)p;   p += 1024 * 4;
    int*   bstart  = (int*)p;   p += 1024 * 4;
    int*   part    = (int*)p;   p += NBLK * 4;
    int*   perm    = (int*)p;   p += (size_t)NN * 4;
    int*   inv_perm= (int*)p;   p += (size_t)NN * 4;
    int*   flag    = (int*)p;   p += 4;

    zero_flag_k<<<1, 64, 0, stream>>>(flag);
    detect_k<<<4, 256, 0, stream>>>((const int*)edges, flag);
    init_k<<<(NN + 255) / 256, 256, 0, stream>>>(dacc, NN);
    count_k<<<(NE + 255) / 256, 256, 0, stream>>>(edges, flag, dacc, rank, NE);
    // degree-sorted renumbering (dcompact fused into bh_k; degs into pscatter)
    bh_k<<<NBLK, 256, 0, stream>>>(dacc, deg, bh, NN);
    btot_k<<<1024, 256, 0, stream>>>(bh, tot, NBLK);
    hscan_k<<<1, 1024, 0, stream>>>(tot, bstart);
    bbase_k<<<1024, 256, 0, stream>>>(bh, bstart, NBLK);
    pscatter_k<<<NBLK, 256, 0, stream>>>(deg, bh, perm, inv_perm, deg_s, dinv_s, NN);
    // rp over PADDED slot-space counts (pad fill fused into pwrite)
    ppart_k<<<NBLK, 256, 0, stream>>>(deg_s, part, NN);
    pscan1_k<<<1, 256, 0, stream>>>(part, NBLK);
    pwrite_k<<<NBLK, 256, 0, stream>>>(deg_s, part, rp, col_s, NN);
    // translated CSR (uint16 columns), atomic-free
    scatter_k<<<(NE + 255) / 256, 256, 0, stream>>>(edges, flag, inv_perm, rp, rank,
                                                    col_s, NE);
    // X0 = qe*obj, sequential stream, row-major original order
    hadamard_k<<<(NN * 32 + 255) / 256, 256, 0, stream>>>(
        (const float4*)qe, (const float4*)obj, Xh, NN * 32);

    int mblk = (NN + 127) / 128;                 // 391
    int gemmBigGrid = ((mblk + 7) / 8) * 16;     // 800 (pair-swizzled, 2 col blocks)
    int agg256Grid = ((NN + 63) / 64) * 8;       // 6256
    int agg128Grid = ((NN + 127) / 128) * 8;     // 3128

    // Layer 1 (perm-indirect A staging from row-major X0)
    wconv_k<<<256, 256, 0, stream>>>(W1, B3, 256);
    gemm_f16_k<2, 32, 1><<<gemmBigGrid, 256, 0, stream>>>(Xh, B3, dinv_s, perm, H, NN, 256);
    aggregate_slice_k<256, 0><<<agg256Grid, 256, 0, stream>>>(H, b1, dinv_s, deg_s, rp, col_s,
                                                              perm, Xh, nullptr, NN);
    // Layer 2 (linear panel staging)
    wconv_k<<<256, 256, 0, stream>>>(W2, B3, 256);
    gemm_f16_k<2, 32, 0><<<gemmBigGrid, 256, 0, stream>>>(Xh, B3, dinv_s, perm, H, NN, 256);
    aggregate_slice_k<256, 0><<<agg256Grid, 256, 0, stream>>>(H, b2, dinv_s, deg_s, rp, col_s,
                                                              perm, Xh, nullptr, NN);
    // Layer 3
    wconv_k<<<128, 256, 0, stream>>>(W3, B3, 128);
    gemm_f16_k<1, 16, 0><<<mblk, 256, 0, stream>>>(Xh, B3, dinv_s, perm, H, NN, 128);
    aggregate_slice_k<128, 1><<<agg128Grid, 256, 0, stream>>>(H, b3, dinv_s, deg_s, rp, col_s,
                                                              perm, nullptr, out, NN);
}